// Round 11
// baseline (744.698 us; speedup 1.0000x reference)
//
#include <hip/hip_runtime.h>
#include <math.h>

#define N_NODES 20000
#define N_EDGES 50000
#define NB      1024
#define IND     32
#define HDIM    64

typedef __attribute__((ext_vector_type(8))) short bf16x8;
typedef __attribute__((ext_vector_type(4))) float f32x4;

static inline size_t align_up(size_t x, size_t a) { return (x + a - 1) & ~(a - 1); }

__device__ __forceinline__ float sigmoidf_(float x) {
    return 1.0f / (1.0f + __expf(-x));
}
__device__ __forceinline__ float tanhf_(float x) {
    float xc = fminf(fmaxf(x, -15.0f), 15.0f);
    float e = __expf(2.0f * xc);
    return (e - 1.0f) / (e + 1.0f);
}
__device__ __forceinline__ unsigned pk2(float p0, float p1) {
    unsigned u0 = __float_as_uint(p0) + 0x8000u;
    unsigned u1 = __float_as_uint(p1) + 0x8000u;
    return __builtin_amdgcn_perm(u1, u0, 0x07060302u);
}
__device__ __forceinline__ unsigned bf1(float v) {
    return (__float_as_uint(v) + 0x8000u) >> 16;
}

// ---- fused prep: We2b permute + wsplit + LSTM weight transposes + offsets ----
__global__ void k_prep(const float* __restrict__ We2, const float* __restrict__ be2,
                       short* __restrict__ We2b,
                       const float* __restrict__ Wroot, const float* __restrict__ gwhh,
                       const float* __restrict__ gwih,
                       short* __restrict__ WB1h, short* __restrict__ WB1l,
                       short* __restrict__ WB2h, short* __restrict__ WB2l,
                       const float* __restrict__ lwih, const float* __restrict__ lwhh,
                       float* __restrict__ lwihT, float* __restrict__ lwhhT,
                       const int* __restrict__ batch, int* __restrict__ offs) {
    int bid = blockIdx.x, tid = threadIdx.x;
    if (bid < 1040) {
        int idx = bid * 256 + tid;                 // 0 .. 65*4096-1
        int s = idx >> 12;
        int col = idx & 4095;
        int k = col >> 6, o = col & 63;
        float val = (s < 64) ? We2[k * 4096 + s * 64 + o] : be2[k * 64 + o];
        int dst = s * 4096 + (((o >> 4) * 128 + (k >> 5) * 64 + ((k >> 3) & 3) * 16 + (o & 15)) << 3) + (k & 7);
        We2b[dst] = (short)bf1(val);
    } else if (bid < 1152) {
        int idx = (bid - 1040) * 256 + tid;
        if (idx < 28672) {
            bool b1 = idx < 16384;
            int li = b1 ? idx : idx - 16384;
            int j = li & 7, lane = (li >> 3) & 63, c = (li >> 9) & 1, otile = li >> 10;
            int k = c * 32 + (lane >> 4) * 8 + j;
            int o = otile * 16 + (lane & 15);
            float val;
            if (b1) val = (o < 64) ? Wroot[k * 64 + o] : gwhh[(o - 64) * 64 + k];
            else    val = gwih[o * 64 + k];
            unsigned hs = bf1(val);
            float lo = val - __uint_as_float(hs << 16);
            unsigned ls = bf1(lo);
            if (b1) { WB1h[li] = (short)hs; WB1l[li] = (short)ls; }
            else    { WB2h[li] = (short)hs; WB2l[li] = (short)ls; }
        }
    } else if (bid < 1280) {
        int idx = (bid - 1152) * 256 + tid;        // < 32768 : lwihT[i*256+j] = lwih[j*128+i]
        int i = idx >> 8, j = idx & 255;
        lwihT[idx] = lwih[j * 128 + i];
    } else if (bid < 1344) {
        int idx = (bid - 1280) * 256 + tid;        // < 16384 : lwhhT[i*256+j] = lwhh[j*64+i]
        int i = idx >> 8, j = idx & 255;
        lwhhT[idx] = lwhh[j * 64 + i];
    } else {
        int i = (bid - 1344) * 256 + tid;
        if (i <= NB) {
            int lo = 0, hi = N_NODES;
            while (lo < hi) { int mid = (lo + hi) >> 1; if (batch[mid] < i) lo = mid + 1; else hi = mid; }
            offs[i] = lo;
        }
    }
}

// ---- CSR build ----
__global__ void k_count(const int* __restrict__ ei, int* __restrict__ deg) {
    int e = blockIdx.x * 256 + threadIdx.x;
    if (e < N_EDGES) atomicAdd(&deg[ei[N_EDGES + e]], 1);
}

__global__ void k_scan(const int* __restrict__ deg, int* __restrict__ rowptr, int* __restrict__ cursor) {
    __shared__ int s_w[16];
    int t = threadIdx.x;
    int base = t * 20;
    int v[20]; int s = 0;
#pragma unroll
    for (int i = 0; i < 20; ++i) {
        int idx = base + i;
        v[i] = (idx < N_NODES) ? deg[idx] : 0;
        s += v[i];
    }
    int lane = t & 63, w = t >> 6;
    int inc = s;
#pragma unroll
    for (int off = 1; off < 64; off <<= 1) {
        int o = __shfl_up(inc, off);
        if (lane >= off) inc += o;
    }
    if (lane == 63) s_w[w] = inc;
    __syncthreads();
    if (w == 0 && lane < 16) {
        int x = s_w[lane];
        int xs = x;
#pragma unroll
        for (int off = 1; off < 16; off <<= 1) {
            int o = __shfl_up(xs, off);
            if (lane >= off) xs += o;
        }
        s_w[lane] = xs - x;
    }
    __syncthreads();
    int run = s_w[w] + (inc - s);
#pragma unroll
    for (int i = 0; i < 20; ++i) {
        int idx = base + i;
        if (idx < N_NODES) { rowptr[idx] = run; cursor[idx] = run; }
        else if (idx == N_NODES) rowptr[idx] = run;
        run += v[i];
    }
}

__global__ void k_fill(const int* __restrict__ ei, int* __restrict__ cursor, int* __restrict__ perm) {
    int e = blockIdx.x * 256 + threadIdx.x;
    if (e < N_EDGES) {
        int pos = atomicAdd(&cursor[ei[N_EDGES + e]], 1);
        perm[pos] = e;
    }
}

// ---- fused encoder ----
__global__ void k_init_feat(const float* __restrict__ x, const float* __restrict__ W0,
                            const float* __restrict__ b0, float* __restrict__ hbuf,
                            const float* __restrict__ ea, const float* __restrict__ We1,
                            const float* __restrict__ be1, float* __restrict__ re) {
    int bid = blockIdx.x;
    int tid = threadIdx.x;
    int w = tid >> 6, j = tid & 63;
    if (bid < 5000) {
        int n = bid * 4 + w;
        float acc = b0[j];
        const float* xr = x + n * IND;
#pragma unroll
        for (int i = 0; i < IND; ++i) acc = fmaf(xr[i], W0[i * 64 + j], acc);
        hbuf[n * 64 + j] = fmaxf(acc, 0.0f);
    } else {
        int e = (bid - 5000) * 4 + w;
        if (e >= N_EDGES) return;
        float acc = be1[j];
        const float* er = ea + e * 6;
#pragma unroll
        for (int i = 0; i < 6; ++i) acc = fmaf(er[i], We1[i * 64 + j], acc);
        re[e * 64 + j] = fmaxf(acc, 0.0f);
    }
}

// msg kernel — R5 structure, occupancy bound raised to 4 blocks/CU (single change):
// 64 edges/block, 256 threads, VGPR ~84 fits the 128-VGPR budget -> no spill.
__launch_bounds__(256, 4)
__global__ void k_msg_mfma(const float* __restrict__ hbuf, const float* __restrict__ reb,
                           const short* __restrict__ We2b, const int* __restrict__ ei,
                           float* __restrict__ msg) {
    __shared__ float s_v[64][64];    // [h][e]
    int tid = threadIdx.x;
    int eb = blockIdx.x * 64;
    int lane = tid & 63;
    int w = tid >> 6;
    int l15 = lane & 15, lhi = lane >> 4;

    // stage s_v transposed
    {
        int se = tid >> 2;
        int sh = tid & 3;
        int ge = eb + se;
        const float* rowp = (ge < N_EDGES) ? (hbuf + (size_t)ei[ge] * 64) : (const float*)0;
#pragma unroll
        for (int rr4 = 0; rr4 < 4; ++rr4) {
            int hb = rr4 * 16 + sh * 4;
            float4 vv = rowp ? *(const float4*)(rowp + hb) : make_float4(0.f, 0.f, 0.f, 0.f);
            s_v[hb + 0][se] = vv.x; s_v[hb + 1][se] = vv.y;
            s_v[hb + 2][se] = vv.z; s_v[hb + 3][se] = vv.w;
        }
    }

    // pack re A-fragments once
    union U { int4 i4; bf16x8 v; };
    U a_re[4][2];
#pragma unroll
    for (int m = 0; m < 4; ++m) {
        int ge = eb + m * 16 + l15;
        if (ge < N_EDGES) {
            const float* rp = reb + (size_t)ge * 64 + lhi * 8;
            float4 x0 = *(const float4*)(rp);
            float4 x1 = *(const float4*)(rp + 4);
            float4 y0 = *(const float4*)(rp + 32);
            float4 y1 = *(const float4*)(rp + 36);
            a_re[m][0].i4 = make_int4(pk2(x0.x, x0.y), pk2(x0.z, x0.w), pk2(x1.x, x1.y), pk2(x1.z, x1.w));
            a_re[m][1].i4 = make_int4(pk2(y0.x, y0.y), pk2(y0.z, y0.w), pk2(y1.x, y1.y), pk2(y1.z, y1.w));
        } else {
            a_re[m][0].i4 = make_int4(0, 0, 0, 0);
            a_re[m][1].i4 = make_int4(0, 0, 0, 0);
        }
    }

    // B prefetch: 4 rotating register sets, depth 4
    const int4* bp0 = (const int4*)We2b + (w * 128 + lane);   // slab stride = 512 int4
    const int4* bp1 = bp0 + 64;
    int4 Sc0[4], Sc1[4];
#pragma unroll
    for (int j = 0; j < 4; ++j) {
        Sc0[j] = bp0[j * 512];
        Sc1[j] = bp1[j * 512];
    }

    __syncthreads();

    const f32x4 zero4 = {0.f, 0.f, 0.f, 0.f};
    f32x4 macc[4];
#pragma unroll
    for (int m = 0; m < 4; ++m) macc[m] = zero4;

    // v prefetch depth 1
    float4 vv[4], vn[4];
#pragma unroll
    for (int m = 0; m < 4; ++m) vv[m] = *(const float4*)&s_v[0][m * 16 + lhi * 4];

    for (int g = 0; g < 16; ++g) {
#pragma unroll
        for (int j = 0; j < 4; ++j) {
            int s = g * 4 + j;
            int snext = (s < 63) ? (s + 1) : 63;
#pragma unroll
            for (int m = 0; m < 4; ++m)
                vn[m] = *(const float4*)&s_v[snext][m * 16 + lhi * 4];
            U bb0, bb1; bb0.i4 = Sc0[j]; bb1.i4 = Sc1[j];
#pragma unroll
            for (int m = 0; m < 4; ++m) {
                f32x4 t = __builtin_amdgcn_mfma_f32_16x16x32_bf16(a_re[m][0].v, bb0.v, zero4, 0, 0, 0);
                t = __builtin_amdgcn_mfma_f32_16x16x32_bf16(a_re[m][1].v, bb1.v, t, 0, 0, 0);
                macc[m][0] = fmaf(vv[m].x, t[0], macc[m][0]);
                macc[m][1] = fmaf(vv[m].y, t[1], macc[m][1]);
                macc[m][2] = fmaf(vv[m].z, t[2], macc[m][2]);
                macc[m][3] = fmaf(vv[m].w, t[3], macc[m][3]);
            }
            int sload = (s + 4 <= 64) ? (s + 4) : 64;
            Sc0[j] = bp0[sload * 512];
            Sc1[j] = bp1[sload * 512];
#pragma unroll
            for (int m = 0; m < 4; ++m) vv[m] = vn[m];
        }
    }

    // bias slab (set 0 holds slab 64): msg += v @ be2
    {
        U bb0, bb1; bb0.i4 = Sc0[0]; bb1.i4 = Sc1[0];
#pragma unroll
        for (int m = 0; m < 4; ++m) {
            int e = m * 16 + l15;
            U a0, a1;
            a0.i4 = make_int4(
                pk2(s_v[lhi * 8 + 0][e], s_v[lhi * 8 + 1][e]),
                pk2(s_v[lhi * 8 + 2][e], s_v[lhi * 8 + 3][e]),
                pk2(s_v[lhi * 8 + 4][e], s_v[lhi * 8 + 5][e]),
                pk2(s_v[lhi * 8 + 6][e], s_v[lhi * 8 + 7][e]));
            a1.i4 = make_int4(
                pk2(s_v[32 + lhi * 8 + 0][e], s_v[32 + lhi * 8 + 1][e]),
                pk2(s_v[32 + lhi * 8 + 2][e], s_v[32 + lhi * 8 + 3][e]),
                pk2(s_v[32 + lhi * 8 + 4][e], s_v[32 + lhi * 8 + 5][e]),
                pk2(s_v[32 + lhi * 8 + 6][e], s_v[32 + lhi * 8 + 7][e]));
            macc[m] = __builtin_amdgcn_mfma_f32_16x16x32_bf16(a0.v, bb0.v, macc[m], 0, 0, 0);
            macc[m] = __builtin_amdgcn_mfma_f32_16x16x32_bf16(a1.v, bb1.v, macc[m], 0, 0, 0);
        }
    }
    int o = w * 16 + l15;
#pragma unroll
    for (int m = 0; m < 4; ++m) {
#pragma unroll
        for (int r = 0; r < 4; ++r) {
            int el = m * 16 + lhi * 4 + r;
            int ge = eb + el;
            if (ge < N_EDGES) msg[(size_t)ge * 64 + o] = macc[m][r];
        }
    }
}

// MFMA node update: conv + GRU with split-bf16 weights. 32 nodes / block (625 blocks).
__launch_bounds__(256, 4)
__global__ void k_node_update(float* __restrict__ hbuf, const float* __restrict__ msg,
                              const int* __restrict__ rowptr, const int* __restrict__ perm,
                              const short* __restrict__ WB1h, const short* __restrict__ WB1l,
                              const short* __restrict__ WB2h, const short* __restrict__ WB2l,
                              const float* __restrict__ bconv, const float* __restrict__ bih,
                              const float* __restrict__ bhh) {
    __shared__ short s_hh[32][72];
    __shared__ short s_hl[32][72];
    __shared__ short s_mh[32][72];
    __shared__ short s_ml[32][72];
    __shared__ float s_agg[32][68];
    int tid = threadIdx.x;
    int nbase = blockIdx.x * 32;
    int lane = tid & 63, w = tid >> 6;
    int l15 = lane & 15, lhi = lane >> 4;

    {
        int nt = tid >> 3, q = tid & 7;
        int n = nbase + nt;
#pragma unroll
        for (int c4 = 0; c4 < 2; ++c4) {
            int col = q * 8 + c4 * 4;
            float4 v = *(const float4*)&hbuf[(size_t)n * 64 + col];
            unsigned h01 = pk2(v.x, v.y), h23 = pk2(v.z, v.w);
            float f0 = __uint_as_float(h01 << 16);
            float f1 = __uint_as_float(h01 & 0xffff0000u);
            float f2 = __uint_as_float(h23 << 16);
            float f3 = __uint_as_float(h23 & 0xffff0000u);
            unsigned l01 = pk2(v.x - f0, v.y - f1), l23 = pk2(v.z - f2, v.w - f3);
            *(unsigned*)&s_hh[nt][col]     = h01;
            *(unsigned*)&s_hh[nt][col + 2] = h23;
            *(unsigned*)&s_hl[nt][col]     = l01;
            *(unsigned*)&s_hl[nt][col + 2] = l23;
        }
        float4 aggv[2];
#pragma unroll
        for (int c4 = 0; c4 < 2; ++c4)
            aggv[c4] = *(const float4*)&bconv[q * 8 + c4 * 4];
        int rs = rowptr[n], rend = rowptr[n + 1];
        for (int qq = rs; qq < rend; ++qq) {
            const float* mrow = msg + (size_t)perm[qq] * 64 + q * 8;
#pragma unroll
            for (int c4 = 0; c4 < 2; ++c4) {
                float4 mv = *(const float4*)&mrow[c4 * 4];
                aggv[c4].x += mv.x; aggv[c4].y += mv.y;
                aggv[c4].z += mv.z; aggv[c4].w += mv.w;
            }
        }
#pragma unroll
        for (int c4 = 0; c4 < 2; ++c4)
            *(float4*)&s_agg[nt][q * 8 + c4 * 4] = aggv[c4];
    }
    __syncthreads();

    union U { int4 i4; bf16x8 v; };
    U ah[2][2], al[2][2];
#pragma unroll
    for (int m = 0; m < 2; ++m)
#pragma unroll
        for (int c = 0; c < 2; ++c) {
            ah[m][c].i4 = *(const int4*)&s_hh[m * 16 + l15][c * 32 + lhi * 8];
            al[m][c].i4 = *(const int4*)&s_hl[m * 16 + l15][c * 32 + lhi * 8];
        }

    const int4* B1h = (const int4*)WB1h;
    const int4* B1l = (const int4*)WB1l;
    const int4* B2h = (const int4*)WB2h;
    const int4* B2l = (const int4*)WB2l;

    f32x4 C0[2], G[3][2], I[3][2];

    {
        int ot = w;
        U bh0, bh1, bl0, bl1;
        bh0.i4 = B1h[(ot * 2 + 0) * 64 + lane];
        bh1.i4 = B1h[(ot * 2 + 1) * 64 + lane];
        bl0.i4 = B1l[(ot * 2 + 0) * 64 + lane];
        bl1.i4 = B1l[(ot * 2 + 1) * 64 + lane];
#pragma unroll
        for (int m = 0; m < 2; ++m) {
            f32x4 c;
#pragma unroll
            for (int r = 0; r < 4; ++r) c[r] = s_agg[m * 16 + lhi * 4 + r][w * 16 + l15];
            c = __builtin_amdgcn_mfma_f32_16x16x32_bf16(ah[m][0].v, bh0.v, c, 0, 0, 0);
            c = __builtin_amdgcn_mfma_f32_16x16x32_bf16(ah[m][1].v, bh1.v, c, 0, 0, 0);
            c = __builtin_amdgcn_mfma_f32_16x16x32_bf16(al[m][0].v, bh0.v, c, 0, 0, 0);
            c = __builtin_amdgcn_mfma_f32_16x16x32_bf16(al[m][1].v, bh1.v, c, 0, 0, 0);
            c = __builtin_amdgcn_mfma_f32_16x16x32_bf16(ah[m][0].v, bl0.v, c, 0, 0, 0);
            c = __builtin_amdgcn_mfma_f32_16x16x32_bf16(ah[m][1].v, bl1.v, c, 0, 0, 0);
            C0[m] = c;
        }
    }
#pragma unroll
    for (int m = 0; m < 2; ++m)
#pragma unroll
        for (int r = 0; r < 4; ++r) {
            float mv = fmaxf(C0[m][r], 0.0f);
            int row = m * 16 + lhi * 4 + r, col = w * 16 + l15;
            unsigned hs = bf1(mv);
            float lof = mv - __uint_as_float(hs << 16);
            s_mh[row][col] = (short)hs;
            s_ml[row][col] = (short)bf1(lof);
        }
#pragma unroll
    for (int p = 1; p < 4; ++p) {
        int ot = p * 4 + w;
        U bh0, bh1, bl0, bl1;
        bh0.i4 = B1h[(ot * 2 + 0) * 64 + lane];
        bh1.i4 = B1h[(ot * 2 + 1) * 64 + lane];
        bl0.i4 = B1l[(ot * 2 + 0) * 64 + lane];
        bl1.i4 = B1l[(ot * 2 + 1) * 64 + lane];
        float bv = bhh[(p - 1) * 64 + w * 16 + l15];
#pragma unroll
        for (int m = 0; m < 2; ++m) {
            f32x4 c = {bv, bv, bv, bv};
            c = __builtin_amdgcn_mfma_f32_16x16x32_bf16(ah[m][0].v, bh0.v, c, 0, 0, 0);
            c = __builtin_amdgcn_mfma_f32_16x16x32_bf16(ah[m][1].v, bh1.v, c, 0, 0, 0);
            c = __builtin_amdgcn_mfma_f32_16x16x32_bf16(al[m][0].v, bh0.v, c, 0, 0, 0);
            c = __builtin_amdgcn_mfma_f32_16x16x32_bf16(al[m][1].v, bh1.v, c, 0, 0, 0);
            c = __builtin_amdgcn_mfma_f32_16x16x32_bf16(ah[m][0].v, bl0.v, c, 0, 0, 0);
            c = __builtin_amdgcn_mfma_f32_16x16x32_bf16(ah[m][1].v, bl1.v, c, 0, 0, 0);
            G[p - 1][m] = c;
        }
    }
    __syncthreads();
    U mh[2][2], ml[2][2];
#pragma unroll
    for (int m = 0; m < 2; ++m)
#pragma unroll
        for (int c = 0; c < 2; ++c) {
            mh[m][c].i4 = *(const int4*)&s_mh[m * 16 + l15][c * 32 + lhi * 8];
            ml[m][c].i4 = *(const int4*)&s_ml[m * 16 + l15][c * 32 + lhi * 8];
        }
#pragma unroll
    for (int p = 0; p < 3; ++p) {
        int ot = p * 4 + w;
        U bh0, bh1, bl0, bl1;
        bh0.i4 = B2h[(ot * 2 + 0) * 64 + lane];
        bh1.i4 = B2h[(ot * 2 + 1) * 64 + lane];
        bl0.i4 = B2l[(ot * 2 + 0) * 64 + lane];
        bl1.i4 = B2l[(ot * 2 + 1) * 64 + lane];
        float bv = bih[p * 64 + w * 16 + l15];
#pragma unroll
        for (int m = 0; m < 2; ++m) {
            f32x4 c = {bv, bv, bv, bv};
            c = __builtin_amdgcn_mfma_f32_16x16x32_bf16(mh[m][0].v, bh0.v, c, 0, 0, 0);
            c = __builtin_amdgcn_mfma_f32_16x16x32_bf16(mh[m][1].v, bh1.v, c, 0, 0, 0);
            c = __builtin_amdgcn_mfma_f32_16x16x32_bf16(ml[m][0].v, bh0.v, c, 0, 0, 0);
            c = __builtin_amdgcn_mfma_f32_16x16x32_bf16(ml[m][1].v, bh1.v, c, 0, 0, 0);
            c = __builtin_amdgcn_mfma_f32_16x16x32_bf16(mh[m][0].v, bl0.v, c, 0, 0, 0);
            c = __builtin_amdgcn_mfma_f32_16x16x32_bf16(mh[m][1].v, bl1.v, c, 0, 0, 0);
            I[p][m] = c;
        }
    }
#pragma unroll
    for (int m = 0; m < 2; ++m)
#pragma unroll
        for (int r = 0; r < 4; ++r) {
            int row = m * 16 + lhi * 4 + r;
            int n = nbase + row;
            int col = w * 16 + l15;
            float hold = __uint_as_float(((unsigned)(unsigned short)s_hh[row][col]) << 16)
                       + __uint_as_float(((unsigned)(unsigned short)s_hl[row][col]) << 16);
            float rg = sigmoidf_(I[0][m][r] + G[0][m][r]);
            float z  = sigmoidf_(I[1][m][r] + G[1][m][r]);
            float nn = tanhf_(I[2][m][r] + rg * G[2][m][r]);
            hbuf[(size_t)n * 64 + col] = (1.0f - z) * nn + z * hold;
        }
}

// Fused Set2Set (3 iterations) + readout MLP. 256 threads (4 waves) per graph.
__launch_bounds__(256)
__global__ void k_set2set(const float* __restrict__ hbuf, const int* __restrict__ offs,
                          const float* __restrict__ t, const float* __restrict__ p,
                          const float* __restrict__ lwihT, const float* __restrict__ lwhhT,
                          const float* __restrict__ l_bih, const float* __restrict__ l_bhh,
                          const float* __restrict__ W1, const float* __restrict__ b1,
                          const float* __restrict__ W2, const float* __restrict__ b2,
                          const float* __restrict__ W3, const float* __restrict__ b3,
                          float* __restrict__ y) {
    __shared__ float s_qs[192];       // [0..127]=q_star, [128..191]=qh
    __shared__ float s_g[256];
    __shared__ float s_racc[4][64];
    __shared__ float s_m[4], s_l[4];
    __shared__ float s_y[64];
    int b = blockIdx.x;
    int tid = threadIdx.x;
    int w = tid >> 6, lane = tid & 63;
    int s = offs[b], e = offs[b + 1];
    float bi = l_bih[tid] + l_bhh[tid];
    float qc = 0.f;                   // live in wave-0 lanes

    if (tid < 192) s_qs[tid] = 0.f;
    __syncthreads();

    for (int iter = 0; iter < 3; ++iter) {
        // ---- gates: 256 outputs, one per thread ----
        float g = bi;
#pragma unroll 8
        for (int i = 0; i < 128; ++i) g = fmaf(s_qs[i], lwihT[i * 256 + tid], g);
#pragma unroll 8
        for (int i = 0; i < 64; ++i)  g = fmaf(s_qs[128 + i], lwhhT[i * 256 + tid], g);
        s_g[tid] = g;
        __syncthreads();
        // ---- LSTM cell update (wave 0) ----
        if (w == 0) {
            float ci = sigmoidf_(s_g[lane]);
            float cf = sigmoidf_(s_g[64 + lane]);
            float cg = tanhf_(s_g[128 + lane]);
            float co = sigmoidf_(s_g[192 + lane]);
            qc = cf * qc + ci * cg;
            float qh = co * tanhf_(qc);
            s_qs[lane] = qh;          // q (first half of q_star)
            s_qs[128 + lane] = qh;    // qh state
        }
        __syncthreads();
        // ---- attention: nodes round-robin across 4 waves ----
        float qv = s_qs[128 + lane];
        float mx = -1e30f, l = 0.0f, racc = 0.0f;
        for (int n = s + w; n < e; n += 4) {
            float xv = hbuf[(size_t)n * 64 + lane];
            float prod = xv * qv;
#pragma unroll
            for (int off = 32; off > 0; off >>= 1) prod += __shfl_xor(prod, off);
            float mnew = fmaxf(mx, prod);
            float scale = __expf(mx - mnew);
            float wgt = __expf(prod - mnew);
            l = l * scale + wgt;
            racc = racc * scale + wgt * xv;
            mx = mnew;
        }
        s_racc[w][lane] = racc;
        if (lane == 0) { s_m[w] = mx; s_l[w] = l; }
        __syncthreads();
        // ---- merge partials (wave 0) ----
        if (w == 0) {
            float M = fmaxf(fmaxf(s_m[0], s_m[1]), fmaxf(s_m[2], s_m[3]));
            float L = 0.f, R = 0.f;
#pragma unroll
            for (int ww = 0; ww < 4; ++ww) {
                float sc = __expf(s_m[ww] - M);
                L += s_l[ww] * sc;
                R = fmaf(s_racc[ww][lane], sc, R);
            }
            s_qs[64 + lane] = (e > s) ? (R / L) : 0.0f;
        }
        __syncthreads();
    }
    // ---- readout (wave 0) ----
    if (w == 0) {
        float acc = b1[lane];
#pragma unroll 8
        for (int i = 0; i < 128; ++i) acc = fmaf(s_qs[i], W1[i * 64 + lane], acc);
        acc = fmaf(t[b], W1[128 * 64 + lane], acc);
        acc = fmaf(p[b], W1[129 * 64 + lane], acc);
        acc = fmaxf(acc, 0.0f);
        s_y[lane] = acc;
        float acc2 = b2[lane];
#pragma unroll 8
        for (int i = 0; i < 64; ++i) acc2 = fmaf(s_y[i], W2[i * 64 + lane], acc2);
        acc2 = fmaxf(acc2, 0.0f);
        float part = acc2 * W3[lane];
#pragma unroll
        for (int off = 32; off > 0; off >>= 1) part += __shfl_xor(part, off);
        if (lane == 0) y[b] = part + b3[0];
    }
}

extern "C" void kernel_launch(void* const* d_in, const int* in_sizes, int n_in,
                              void* d_out, int out_size, void* d_ws, size_t ws_size,
                              hipStream_t stream) {
    const float* x     = (const float*)d_in[0];
    const int*   ei    = (const int*)  d_in[1];
    const float* ea    = (const float*)d_in[2];
    const int*   batch = (const int*)  d_in[3];
    const float* t     = (const float*)d_in[4];
    const float* p     = (const float*)d_in[5];
    const float* W0    = (const float*)d_in[7];
    const float* b0    = (const float*)d_in[8];
    const float* We1   = (const float*)d_in[9];
    const float* be1   = (const float*)d_in[10];
    const float* We2   = (const float*)d_in[11];
    const float* be2   = (const float*)d_in[12];
    const float* Wroot = (const float*)d_in[13];
    const float* bconv = (const float*)d_in[14];
    const float* gwih  = (const float*)d_in[15];
    const float* gwhh  = (const float*)d_in[16];
    const float* gbih  = (const float*)d_in[17];
    const float* gbhh  = (const float*)d_in[18];
    const float* lwih  = (const float*)d_in[19];
    const float* lwhh  = (const float*)d_in[20];
    const float* lbih  = (const float*)d_in[21];
    const float* lbhh  = (const float*)d_in[22];
    const float* W1    = (const float*)d_in[23];
    const float* b1    = (const float*)d_in[24];
    const float* W2    = (const float*)d_in[25];
    const float* b2    = (const float*)d_in[26];
    const float* W3    = (const float*)d_in[27];
    const float* b3    = (const float*)d_in[28];
    float* y = (float*)d_out;

    char* ws = (char*)d_ws;
    size_t off = 0;
    auto alloc = [&](size_t nbytes) {
        void* ptr = (void*)(ws + off);
        off += align_up(nbytes, 256);
        return ptr;
    };
    float* hbuf   = (float*)alloc((size_t)N_NODES * 64 * 4);
    float* reb    = (float*)alloc((size_t)N_EDGES * 64 * 4);
    float* msg    = (float*)alloc((size_t)N_EDGES * 64 * 4);
    short* We2b   = (short*)alloc((size_t)65 * 4096 * 2);
    short* WB1h   = (short*)alloc(16384 * 2);
    short* WB1l   = (short*)alloc(16384 * 2);
    short* WB2h   = (short*)alloc(12288 * 2);
    short* WB2l   = (short*)alloc(12288 * 2);
    float* lwihT  = (float*)alloc(32768 * 4);
    float* lwhhT  = (float*)alloc(16384 * 4);
    int*   offs   = (int*)  alloc((NB + 1) * 4);
    int*   deg    = (int*)  alloc(N_NODES * 4);
    int*   rowptr = (int*)  alloc((N_NODES + 1) * 4);
    int*   cursor = (int*)  alloc(N_NODES * 4);
    int*   perm   = (int*)  alloc(N_EDGES * 4);

    // ---- prep (fused) + CSR ----
    k_prep<<<1349, 256, 0, stream>>>(We2, be2, We2b, Wroot, gwhh, gwih,
                                     WB1h, WB1l, WB2h, WB2l,
                                     lwih, lwhh, lwihT, lwhhT, batch, offs);
    hipMemsetAsync(deg, 0, (size_t)N_NODES * 4, stream);
    k_count<<<(N_EDGES + 255) / 256, 256, 0, stream>>>(ei, deg);
    k_scan<<<1, 1024, 0, stream>>>(deg, rowptr, cursor);
    k_fill<<<(N_EDGES + 255) / 256, 256, 0, stream>>>(ei, cursor, perm);

    // ---- encoder (fused) ----
    k_init_feat<<<17500, 256, 0, stream>>>(x, W0, b0, hbuf, ea, We1, be1, reb);

    // ---- 4 message-passing + GRU iterations ----
    for (int it = 0; it < 4; ++it) {
        k_msg_mfma<<<(N_EDGES + 63) / 64, 256, 0, stream>>>(hbuf, reb, We2b, ei, msg);
        k_node_update<<<N_NODES / 32, 256, 0, stream>>>(hbuf, msg, rowptr, perm,
                                                        WB1h, WB1l, WB2h, WB2l,
                                                        bconv, gbih, gbhh);
    }

    // ---- fused Set2Set (3 iters) + readout ----
    k_set2set<<<NB, 256, 0, stream>>>(hbuf, offs, t, p, lwihT, lwhhT, lbih, lbhh,
                                      W1, b1, W2, b2, W3, b3, y);
}

// Round 12
// 469.381 us; speedup vs baseline: 1.5866x; 1.5866x over previous
//
#include <hip/hip_runtime.h>
#include <math.h>

#define N_NODES 20000
#define N_EDGES 50000
#define NB      1024
#define IND     32
#define HDIM    64

typedef __attribute__((ext_vector_type(8))) short bf16x8;
typedef __attribute__((ext_vector_type(4))) float f32x4;

static inline size_t align_up(size_t x, size_t a) { return (x + a - 1) & ~(a - 1); }

__device__ __forceinline__ float sigmoidf_(float x) {
    return 1.0f / (1.0f + __expf(-x));
}
__device__ __forceinline__ float tanhf_(float x) {
    float xc = fminf(fmaxf(x, -15.0f), 15.0f);
    float e = __expf(2.0f * xc);
    return (e - 1.0f) / (e + 1.0f);
}
__device__ __forceinline__ unsigned pk2(float p0, float p1) {
    unsigned u0 = __float_as_uint(p0) + 0x8000u;
    unsigned u1 = __float_as_uint(p1) + 0x8000u;
    return __builtin_amdgcn_perm(u1, u0, 0x07060302u);
}
__device__ __forceinline__ unsigned bf1(float v) {
    return (__float_as_uint(v) + 0x8000u) >> 16;
}

// ---- fused prep: We2b permute + wsplit + LSTM weight transposes + offsets ----
__global__ void k_prep(const float* __restrict__ We2, const float* __restrict__ be2,
                       short* __restrict__ We2b,
                       const float* __restrict__ Wroot, const float* __restrict__ gwhh,
                       const float* __restrict__ gwih,
                       short* __restrict__ WB1h, short* __restrict__ WB1l,
                       short* __restrict__ WB2h, short* __restrict__ WB2l,
                       const float* __restrict__ lwih, const float* __restrict__ lwhh,
                       float* __restrict__ lwihT, float* __restrict__ lwhhT,
                       const int* __restrict__ batch, int* __restrict__ offs) {
    int bid = blockIdx.x, tid = threadIdx.x;
    if (bid < 1040) {
        int idx = bid * 256 + tid;                 // 0 .. 65*4096-1
        int s = idx >> 12;
        int col = idx & 4095;
        int k = col >> 6, o = col & 63;
        float val = (s < 64) ? We2[k * 4096 + s * 64 + o] : be2[k * 64 + o];
        int dst = s * 4096 + (((o >> 4) * 128 + (k >> 5) * 64 + ((k >> 3) & 3) * 16 + (o & 15)) << 3) + (k & 7);
        We2b[dst] = (short)bf1(val);
    } else if (bid < 1152) {
        int idx = (bid - 1040) * 256 + tid;
        if (idx < 28672) {
            bool b1 = idx < 16384;
            int li = b1 ? idx : idx - 16384;
            int j = li & 7, lane = (li >> 3) & 63, c = (li >> 9) & 1, otile = li >> 10;
            int k = c * 32 + (lane >> 4) * 8 + j;
            int o = otile * 16 + (lane & 15);
            float val;
            if (b1) val = (o < 64) ? Wroot[k * 64 + o] : gwhh[(o - 64) * 64 + k];
            else    val = gwih[o * 64 + k];
            unsigned hs = bf1(val);
            float lo = val - __uint_as_float(hs << 16);
            unsigned ls = bf1(lo);
            if (b1) { WB1h[li] = (short)hs; WB1l[li] = (short)ls; }
            else    { WB2h[li] = (short)hs; WB2l[li] = (short)ls; }
        }
    } else if (bid < 1280) {
        int idx = (bid - 1152) * 256 + tid;        // < 32768 : lwihT[i*256+j] = lwih[j*128+i]
        int i = idx >> 8, j = idx & 255;
        lwihT[idx] = lwih[j * 128 + i];
    } else if (bid < 1344) {
        int idx = (bid - 1280) * 256 + tid;        // < 16384 : lwhhT[i*256+j] = lwhh[j*64+i]
        int i = idx >> 8, j = idx & 255;
        lwhhT[idx] = lwhh[j * 64 + i];
    } else {
        int i = (bid - 1344) * 256 + tid;
        if (i <= NB) {
            int lo = 0, hi = N_NODES;
            while (lo < hi) { int mid = (lo + hi) >> 1; if (batch[mid] < i) lo = mid + 1; else hi = mid; }
            offs[i] = lo;
        }
    }
}

// ---- CSR build ----
__global__ void k_count(const int* __restrict__ ei, int* __restrict__ deg) {
    int e = blockIdx.x * 256 + threadIdx.x;
    if (e < N_EDGES) atomicAdd(&deg[ei[N_EDGES + e]], 1);
}

__global__ void k_scan(const int* __restrict__ deg, int* __restrict__ rowptr, int* __restrict__ cursor) {
    __shared__ int s_w[16];
    int t = threadIdx.x;
    int base = t * 20;
    int v[20]; int s = 0;
#pragma unroll
    for (int i = 0; i < 20; ++i) {
        int idx = base + i;
        v[i] = (idx < N_NODES) ? deg[idx] : 0;
        s += v[i];
    }
    int lane = t & 63, w = t >> 6;
    int inc = s;
#pragma unroll
    for (int off = 1; off < 64; off <<= 1) {
        int o = __shfl_up(inc, off);
        if (lane >= off) inc += o;
    }
    if (lane == 63) s_w[w] = inc;
    __syncthreads();
    if (w == 0 && lane < 16) {
        int x = s_w[lane];
        int xs = x;
#pragma unroll
        for (int off = 1; off < 16; off <<= 1) {
            int o = __shfl_up(xs, off);
            if (lane >= off) xs += o;
        }
        s_w[lane] = xs - x;
    }
    __syncthreads();
    int run = s_w[w] + (inc - s);
#pragma unroll
    for (int i = 0; i < 20; ++i) {
        int idx = base + i;
        if (idx < N_NODES) { rowptr[idx] = run; cursor[idx] = run; }
        else if (idx == N_NODES) rowptr[idx] = run;
        run += v[i];
    }
}

__global__ void k_fill(const int* __restrict__ ei, int* __restrict__ cursor, int* __restrict__ perm) {
    int e = blockIdx.x * 256 + threadIdx.x;
    if (e < N_EDGES) {
        int pos = atomicAdd(&cursor[ei[N_EDGES + e]], 1);
        perm[pos] = e;
    }
}

// ---- fused encoder ----
__global__ void k_init_feat(const float* __restrict__ x, const float* __restrict__ W0,
                            const float* __restrict__ b0, float* __restrict__ hbuf,
                            const float* __restrict__ ea, const float* __restrict__ We1,
                            const float* __restrict__ be1, float* __restrict__ re) {
    int bid = blockIdx.x;
    int tid = threadIdx.x;
    int w = tid >> 6, j = tid & 63;
    if (bid < 5000) {
        int n = bid * 4 + w;
        float acc = b0[j];
        const float* xr = x + n * IND;
#pragma unroll
        for (int i = 0; i < IND; ++i) acc = fmaf(xr[i], W0[i * 64 + j], acc);
        hbuf[n * 64 + j] = fmaxf(acc, 0.0f);
    } else {
        int e = (bid - 5000) * 4 + w;
        if (e >= N_EDGES) return;
        float acc = be1[j];
        const float* er = ea + e * 6;
#pragma unroll
        for (int i = 0; i < 6; ++i) acc = fmaf(er[i], We1[i * 64 + j], acc);
        re[e * 64 + j] = fmaxf(acc, 0.0f);
    }
}

// msg kernel — split-K ACROSS BLOCKS: grid = 2*tiles. bid>>1 = 64-edge tile, bid&1 = h-half.
// Each block: identical 256-thread/84-VGPR structure as the verified R5 kernel, but only
// 32 h-slabs (half 1 also adds the bias slab). Half 0 -> msgA, half 1 -> msgB;
// node_update sums both. (256,3): proven no-spill; occupancy now grid-limited ~6 blocks/CU.
__launch_bounds__(256, 3)
__global__ void k_msg_mfma(const float* __restrict__ hbuf, const float* __restrict__ reb,
                           const short* __restrict__ We2b, const int* __restrict__ ei,
                           float* __restrict__ msgA, float* __restrict__ msgB) {
    __shared__ float s_v[64][64];    // [h][e]
    int tid = threadIdx.x;
    int tile = blockIdx.x >> 1;
    int half = blockIdx.x & 1;
    int eb = tile * 64;
    int lane = tid & 63;
    int w = tid >> 6;
    int l15 = lane & 15, lhi = lane >> 4;

    // stage s_v transposed (full 64 h rows; bias pass in half 1 needs them all)
    {
        int se = tid >> 2;
        int sh = tid & 3;
        int ge = eb + se;
        const float* rowp = (ge < N_EDGES) ? (hbuf + (size_t)ei[ge] * 64) : (const float*)0;
#pragma unroll
        for (int rr4 = 0; rr4 < 4; ++rr4) {
            int hb = rr4 * 16 + sh * 4;
            float4 vv = rowp ? *(const float4*)(rowp + hb) : make_float4(0.f, 0.f, 0.f, 0.f);
            s_v[hb + 0][se] = vv.x; s_v[hb + 1][se] = vv.y;
            s_v[hb + 2][se] = vv.z; s_v[hb + 3][se] = vv.w;
        }
    }

    // pack re A-fragments once (same for both halves)
    union U { int4 i4; bf16x8 v; };
    U a_re[4][2];
#pragma unroll
    for (int m = 0; m < 4; ++m) {
        int ge = eb + m * 16 + l15;
        if (ge < N_EDGES) {
            const float* rp = reb + (size_t)ge * 64 + lhi * 8;
            float4 x0 = *(const float4*)(rp);
            float4 x1 = *(const float4*)(rp + 4);
            float4 y0 = *(const float4*)(rp + 32);
            float4 y1 = *(const float4*)(rp + 36);
            a_re[m][0].i4 = make_int4(pk2(x0.x, x0.y), pk2(x0.z, x0.w), pk2(x1.x, x1.y), pk2(x1.z, x1.w));
            a_re[m][1].i4 = make_int4(pk2(y0.x, y0.y), pk2(y0.z, y0.w), pk2(y1.x, y1.y), pk2(y1.z, y1.w));
        } else {
            a_re[m][0].i4 = make_int4(0, 0, 0, 0);
            a_re[m][1].i4 = make_int4(0, 0, 0, 0);
        }
    }

    // B prefetch: 4 rotating register sets, depth 4; slab base = half*32
    int hbase = half * 32;
    const int4* bp0 = (const int4*)We2b + (w * 128 + lane);   // slab stride = 512 int4
    const int4* bp1 = bp0 + 64;
    int4 Sc0[4], Sc1[4];
#pragma unroll
    for (int j = 0; j < 4; ++j) {
        Sc0[j] = bp0[(size_t)(hbase + j) * 512];
        Sc1[j] = bp1[(size_t)(hbase + j) * 512];
    }

    __syncthreads();

    const f32x4 zero4 = {0.f, 0.f, 0.f, 0.f};
    f32x4 macc[4];
#pragma unroll
    for (int m = 0; m < 4; ++m) macc[m] = zero4;

    // v prefetch depth 1
    float4 vv[4], vn[4];
#pragma unroll
    for (int m = 0; m < 4; ++m) vv[m] = *(const float4*)&s_v[hbase][m * 16 + lhi * 4];

    for (int g = 0; g < 8; ++g) {
#pragma unroll
        for (int j = 0; j < 4; ++j) {
            int s = g * 4 + j;                   // local slab 0..31
            int snext = (s < 31) ? (hbase + s + 1) : (hbase + 31);
#pragma unroll
            for (int m = 0; m < 4; ++m)
                vn[m] = *(const float4*)&s_v[snext][m * 16 + lhi * 4];
            U bb0, bb1; bb0.i4 = Sc0[j]; bb1.i4 = Sc1[j];
#pragma unroll
            for (int m = 0; m < 4; ++m) {
                f32x4 t = __builtin_amdgcn_mfma_f32_16x16x32_bf16(a_re[m][0].v, bb0.v, zero4, 0, 0, 0);
                t = __builtin_amdgcn_mfma_f32_16x16x32_bf16(a_re[m][1].v, bb1.v, t, 0, 0, 0);
                macc[m][0] = fmaf(vv[m].x, t[0], macc[m][0]);
                macc[m][1] = fmaf(vv[m].y, t[1], macc[m][1]);
                macc[m][2] = fmaf(vv[m].z, t[2], macc[m][2]);
                macc[m][3] = fmaf(vv[m].w, t[3], macc[m][3]);
            }
            int gslab = hbase + s + 4;           // prefetch; clamp into We2b's 65 slabs
            if (gslab > 64) gslab = 64;          // half1 tail -> bias slab lands in all sets
            Sc0[j] = bp0[(size_t)gslab * 512];
            Sc1[j] = bp1[(size_t)gslab * 512];
#pragma unroll
            for (int m = 0; m < 4; ++m) vv[m] = vn[m];
        }
    }

    if (half == 1) {
        // bias slab (set 0 holds slab 64): msg += v @ be2
        U bb0, bb1; bb0.i4 = Sc0[0]; bb1.i4 = Sc1[0];
#pragma unroll
        for (int m = 0; m < 4; ++m) {
            int e = m * 16 + l15;
            U a0, a1;
            a0.i4 = make_int4(
                pk2(s_v[lhi * 8 + 0][e], s_v[lhi * 8 + 1][e]),
                pk2(s_v[lhi * 8 + 2][e], s_v[lhi * 8 + 3][e]),
                pk2(s_v[lhi * 8 + 4][e], s_v[lhi * 8 + 5][e]),
                pk2(s_v[lhi * 8 + 6][e], s_v[lhi * 8 + 7][e]));
            a1.i4 = make_int4(
                pk2(s_v[32 + lhi * 8 + 0][e], s_v[32 + lhi * 8 + 1][e]),
                pk2(s_v[32 + lhi * 8 + 2][e], s_v[32 + lhi * 8 + 3][e]),
                pk2(s_v[32 + lhi * 8 + 4][e], s_v[32 + lhi * 8 + 5][e]),
                pk2(s_v[32 + lhi * 8 + 6][e], s_v[32 + lhi * 8 + 7][e]));
            macc[m] = __builtin_amdgcn_mfma_f32_16x16x32_bf16(a0.v, bb0.v, macc[m], 0, 0, 0);
            macc[m] = __builtin_amdgcn_mfma_f32_16x16x32_bf16(a1.v, bb1.v, macc[m], 0, 0, 0);
        }
    }
    float* mout = half ? msgB : msgA;
    int o = w * 16 + l15;
#pragma unroll
    for (int m = 0; m < 4; ++m) {
#pragma unroll
        for (int r = 0; r < 4; ++r) {
            int el = m * 16 + lhi * 4 + r;
            int ge = eb + el;
            if (ge < N_EDGES) mout[(size_t)ge * 64 + o] = macc[m][r];
        }
    }
}

// MFMA node update: conv + GRU with split-bf16 weights. 32 nodes / block (625 blocks).
// Gather sums the two split-K halves msgA + msgB.
__launch_bounds__(256, 4)
__global__ void k_node_update(float* __restrict__ hbuf, const float* __restrict__ msgA,
                              const float* __restrict__ msgB,
                              const int* __restrict__ rowptr, const int* __restrict__ perm,
                              const short* __restrict__ WB1h, const short* __restrict__ WB1l,
                              const short* __restrict__ WB2h, const short* __restrict__ WB2l,
                              const float* __restrict__ bconv, const float* __restrict__ bih,
                              const float* __restrict__ bhh) {
    __shared__ short s_hh[32][72];
    __shared__ short s_hl[32][72];
    __shared__ short s_mh[32][72];
    __shared__ short s_ml[32][72];
    __shared__ float s_agg[32][68];
    int tid = threadIdx.x;
    int nbase = blockIdx.x * 32;
    int lane = tid & 63, w = tid >> 6;
    int l15 = lane & 15, lhi = lane >> 4;

    {
        int nt = tid >> 3, q = tid & 7;
        int n = nbase + nt;
#pragma unroll
        for (int c4 = 0; c4 < 2; ++c4) {
            int col = q * 8 + c4 * 4;
            float4 v = *(const float4*)&hbuf[(size_t)n * 64 + col];
            unsigned h01 = pk2(v.x, v.y), h23 = pk2(v.z, v.w);
            float f0 = __uint_as_float(h01 << 16);
            float f1 = __uint_as_float(h01 & 0xffff0000u);
            float f2 = __uint_as_float(h23 << 16);
            float f3 = __uint_as_float(h23 & 0xffff0000u);
            unsigned l01 = pk2(v.x - f0, v.y - f1), l23 = pk2(v.z - f2, v.w - f3);
            *(unsigned*)&s_hh[nt][col]     = h01;
            *(unsigned*)&s_hh[nt][col + 2] = h23;
            *(unsigned*)&s_hl[nt][col]     = l01;
            *(unsigned*)&s_hl[nt][col + 2] = l23;
        }
        float4 aggv[2];
#pragma unroll
        for (int c4 = 0; c4 < 2; ++c4)
            aggv[c4] = *(const float4*)&bconv[q * 8 + c4 * 4];
        int rs = rowptr[n], rend = rowptr[n + 1];
        for (int qq = rs; qq < rend; ++qq) {
            size_t mbase = (size_t)perm[qq] * 64 + q * 8;
            const float* mrowA = msgA + mbase;
            const float* mrowB = msgB + mbase;
#pragma unroll
            for (int c4 = 0; c4 < 2; ++c4) {
                float4 ma = *(const float4*)&mrowA[c4 * 4];
                float4 mb = *(const float4*)&mrowB[c4 * 4];
                aggv[c4].x += ma.x + mb.x; aggv[c4].y += ma.y + mb.y;
                aggv[c4].z += ma.z + mb.z; aggv[c4].w += ma.w + mb.w;
            }
        }
#pragma unroll
        for (int c4 = 0; c4 < 2; ++c4)
            *(float4*)&s_agg[nt][q * 8 + c4 * 4] = aggv[c4];
    }
    __syncthreads();

    union U { int4 i4; bf16x8 v; };
    U ah[2][2], al[2][2];
#pragma unroll
    for (int m = 0; m < 2; ++m)
#pragma unroll
        for (int c = 0; c < 2; ++c) {
            ah[m][c].i4 = *(const int4*)&s_hh[m * 16 + l15][c * 32 + lhi * 8];
            al[m][c].i4 = *(const int4*)&s_hl[m * 16 + l15][c * 32 + lhi * 8];
        }

    const int4* B1h = (const int4*)WB1h;
    const int4* B1l = (const int4*)WB1l;
    const int4* B2h = (const int4*)WB2h;
    const int4* B2l = (const int4*)WB2l;

    f32x4 C0[2], G[3][2], I[3][2];

    {
        int ot = w;
        U bh0, bh1, bl0, bl1;
        bh0.i4 = B1h[(ot * 2 + 0) * 64 + lane];
        bh1.i4 = B1h[(ot * 2 + 1) * 64 + lane];
        bl0.i4 = B1l[(ot * 2 + 0) * 64 + lane];
        bl1.i4 = B1l[(ot * 2 + 1) * 64 + lane];
#pragma unroll
        for (int m = 0; m < 2; ++m) {
            f32x4 c;
#pragma unroll
            for (int r = 0; r < 4; ++r) c[r] = s_agg[m * 16 + lhi * 4 + r][w * 16 + l15];
            c = __builtin_amdgcn_mfma_f32_16x16x32_bf16(ah[m][0].v, bh0.v, c, 0, 0, 0);
            c = __builtin_amdgcn_mfma_f32_16x16x32_bf16(ah[m][1].v, bh1.v, c, 0, 0, 0);
            c = __builtin_amdgcn_mfma_f32_16x16x32_bf16(al[m][0].v, bh0.v, c, 0, 0, 0);
            c = __builtin_amdgcn_mfma_f32_16x16x32_bf16(al[m][1].v, bh1.v, c, 0, 0, 0);
            c = __builtin_amdgcn_mfma_f32_16x16x32_bf16(ah[m][0].v, bl0.v, c, 0, 0, 0);
            c = __builtin_amdgcn_mfma_f32_16x16x32_bf16(ah[m][1].v, bl1.v, c, 0, 0, 0);
            C0[m] = c;
        }
    }
#pragma unroll
    for (int m = 0; m < 2; ++m)
#pragma unroll
        for (int r = 0; r < 4; ++r) {
            float mv = fmaxf(C0[m][r], 0.0f);
            int row = m * 16 + lhi * 4 + r, col = w * 16 + l15;
            unsigned hs = bf1(mv);
            float lof = mv - __uint_as_float(hs << 16);
            s_mh[row][col] = (short)hs;
            s_ml[row][col] = (short)bf1(lof);
        }
#pragma unroll
    for (int p = 1; p < 4; ++p) {
        int ot = p * 4 + w;
        U bh0, bh1, bl0, bl1;
        bh0.i4 = B1h[(ot * 2 + 0) * 64 + lane];
        bh1.i4 = B1h[(ot * 2 + 1) * 64 + lane];
        bl0.i4 = B1l[(ot * 2 + 0) * 64 + lane];
        bl1.i4 = B1l[(ot * 2 + 1) * 64 + lane];
        float bv = bhh[(p - 1) * 64 + w * 16 + l15];
#pragma unroll
        for (int m = 0; m < 2; ++m) {
            f32x4 c = {bv, bv, bv, bv};
            c = __builtin_amdgcn_mfma_f32_16x16x32_bf16(ah[m][0].v, bh0.v, c, 0, 0, 0);
            c = __builtin_amdgcn_mfma_f32_16x16x32_bf16(ah[m][1].v, bh1.v, c, 0, 0, 0);
            c = __builtin_amdgcn_mfma_f32_16x16x32_bf16(al[m][0].v, bh0.v, c, 0, 0, 0);
            c = __builtin_amdgcn_mfma_f32_16x16x32_bf16(al[m][1].v, bh1.v, c, 0, 0, 0);
            c = __builtin_amdgcn_mfma_f32_16x16x32_bf16(ah[m][0].v, bl0.v, c, 0, 0, 0);
            c = __builtin_amdgcn_mfma_f32_16x16x32_bf16(ah[m][1].v, bl1.v, c, 0, 0, 0);
            G[p - 1][m] = c;
        }
    }
    __syncthreads();
    U mh[2][2], ml[2][2];
#pragma unroll
    for (int m = 0; m < 2; ++m)
#pragma unroll
        for (int c = 0; c < 2; ++c) {
            mh[m][c].i4 = *(const int4*)&s_mh[m * 16 + l15][c * 32 + lhi * 8];
            ml[m][c].i4 = *(const int4*)&s_ml[m * 16 + l15][c * 32 + lhi * 8];
        }
#pragma unroll
    for (int p = 0; p < 3; ++p) {
        int ot = p * 4 + w;
        U bh0, bh1, bl0, bl1;
        bh0.i4 = B2h[(ot * 2 + 0) * 64 + lane];
        bh1.i4 = B2h[(ot * 2 + 1) * 64 + lane];
        bl0.i4 = B2l[(ot * 2 + 0) * 64 + lane];
        bl1.i4 = B2l[(ot * 2 + 1) * 64 + lane];
        float bv = bih[p * 64 + w * 16 + l15];
#pragma unroll
        for (int m = 0; m < 2; ++m) {
            f32x4 c = {bv, bv, bv, bv};
            c = __builtin_amdgcn_mfma_f32_16x16x32_bf16(mh[m][0].v, bh0.v, c, 0, 0, 0);
            c = __builtin_amdgcn_mfma_f32_16x16x32_bf16(mh[m][1].v, bh1.v, c, 0, 0, 0);
            c = __builtin_amdgcn_mfma_f32_16x16x32_bf16(ml[m][0].v, bh0.v, c, 0, 0, 0);
            c = __builtin_amdgcn_mfma_f32_16x16x32_bf16(ml[m][1].v, bh1.v, c, 0, 0, 0);
            c = __builtin_amdgcn_mfma_f32_16x16x32_bf16(mh[m][0].v, bl0.v, c, 0, 0, 0);
            c = __builtin_amdgcn_mfma_f32_16x16x32_bf16(mh[m][1].v, bl1.v, c, 0, 0, 0);
            I[p][m] = c;
        }
    }
#pragma unroll
    for (int m = 0; m < 2; ++m)
#pragma unroll
        for (int r = 0; r < 4; ++r) {
            int row = m * 16 + lhi * 4 + r;
            int n = nbase + row;
            int col = w * 16 + l15;
            float hold = __uint_as_float(((unsigned)(unsigned short)s_hh[row][col]) << 16)
                       + __uint_as_float(((unsigned)(unsigned short)s_hl[row][col]) << 16);
            float rg = sigmoidf_(I[0][m][r] + G[0][m][r]);
            float z  = sigmoidf_(I[1][m][r] + G[1][m][r]);
            float nn = tanhf_(I[2][m][r] + rg * G[2][m][r]);
            hbuf[(size_t)n * 64 + col] = (1.0f - z) * nn + z * hold;
        }
}

// Fused Set2Set (3 iterations) + readout MLP. 256 threads (4 waves) per graph.
__launch_bounds__(256)
__global__ void k_set2set(const float* __restrict__ hbuf, const int* __restrict__ offs,
                          const float* __restrict__ t, const float* __restrict__ p,
                          const float* __restrict__ lwihT, const float* __restrict__ lwhhT,
                          const float* __restrict__ l_bih, const float* __restrict__ l_bhh,
                          const float* __restrict__ W1, const float* __restrict__ b1,
                          const float* __restrict__ W2, const float* __restrict__ b2,
                          const float* __restrict__ W3, const float* __restrict__ b3,
                          float* __restrict__ y) {
    __shared__ float s_qs[192];       // [0..127]=q_star, [128..191]=qh
    __shared__ float s_g[256];
    __shared__ float s_racc[4][64];
    __shared__ float s_m[4], s_l[4];
    __shared__ float s_y[64];
    int b = blockIdx.x;
    int tid = threadIdx.x;
    int w = tid >> 6, lane = tid & 63;
    int s = offs[b], e = offs[b + 1];
    float bi = l_bih[tid] + l_bhh[tid];
    float qc = 0.f;                   // live in wave-0 lanes

    if (tid < 192) s_qs[tid] = 0.f;
    __syncthreads();

    for (int iter = 0; iter < 3; ++iter) {
        // ---- gates: 256 outputs, one per thread ----
        float g = bi;
#pragma unroll 8
        for (int i = 0; i < 128; ++i) g = fmaf(s_qs[i], lwihT[i * 256 + tid], g);
#pragma unroll 8
        for (int i = 0; i < 64; ++i)  g = fmaf(s_qs[128 + i], lwhhT[i * 256 + tid], g);
        s_g[tid] = g;
        __syncthreads();
        // ---- LSTM cell update (wave 0) ----
        if (w == 0) {
            float ci = sigmoidf_(s_g[lane]);
            float cf = sigmoidf_(s_g[64 + lane]);
            float cg = tanhf_(s_g[128 + lane]);
            float co = sigmoidf_(s_g[192 + lane]);
            qc = cf * qc + ci * cg;
            float qh = co * tanhf_(qc);
            s_qs[lane] = qh;          // q (first half of q_star)
            s_qs[128 + lane] = qh;    // qh state
        }
        __syncthreads();
        // ---- attention: nodes round-robin across 4 waves ----
        float qv = s_qs[128 + lane];
        float mx = -1e30f, l = 0.0f, racc = 0.0f;
        for (int n = s + w; n < e; n += 4) {
            float xv = hbuf[(size_t)n * 64 + lane];
            float prod = xv * qv;
#pragma unroll
            for (int off = 32; off > 0; off >>= 1) prod += __shfl_xor(prod, off);
            float mnew = fmaxf(mx, prod);
            float scale = __expf(mx - mnew);
            float wgt = __expf(prod - mnew);
            l = l * scale + wgt;
            racc = racc * scale + wgt * xv;
            mx = mnew;
        }
        s_racc[w][lane] = racc;
        if (lane == 0) { s_m[w] = mx; s_l[w] = l; }
        __syncthreads();
        // ---- merge partials (wave 0) ----
        if (w == 0) {
            float M = fmaxf(fmaxf(s_m[0], s_m[1]), fmaxf(s_m[2], s_m[3]));
            float L = 0.f, R = 0.f;
#pragma unroll
            for (int ww = 0; ww < 4; ++ww) {
                float sc = __expf(s_m[ww] - M);
                L += s_l[ww] * sc;
                R = fmaf(s_racc[ww][lane], sc, R);
            }
            s_qs[64 + lane] = (e > s) ? (R / L) : 0.0f;
        }
        __syncthreads();
    }
    // ---- readout (wave 0) ----
    if (w == 0) {
        float acc = b1[lane];
#pragma unroll 8
        for (int i = 0; i < 128; ++i) acc = fmaf(s_qs[i], W1[i * 64 + lane], acc);
        acc = fmaf(t[b], W1[128 * 64 + lane], acc);
        acc = fmaf(p[b], W1[129 * 64 + lane], acc);
        acc = fmaxf(acc, 0.0f);
        s_y[lane] = acc;
        float acc2 = b2[lane];
#pragma unroll 8
        for (int i = 0; i < 64; ++i) acc2 = fmaf(s_y[i], W2[i * 64 + lane], acc2);
        acc2 = fmaxf(acc2, 0.0f);
        float part = acc2 * W3[lane];
#pragma unroll
        for (int off = 32; off > 0; off >>= 1) part += __shfl_xor(part, off);
        if (lane == 0) y[b] = part + b3[0];
    }
}

extern "C" void kernel_launch(void* const* d_in, const int* in_sizes, int n_in,
                              void* d_out, int out_size, void* d_ws, size_t ws_size,
                              hipStream_t stream) {
    const float* x     = (const float*)d_in[0];
    const int*   ei    = (const int*)  d_in[1];
    const float* ea    = (const float*)d_in[2];
    const int*   batch = (const int*)  d_in[3];
    const float* t     = (const float*)d_in[4];
    const float* p     = (const float*)d_in[5];
    const float* W0    = (const float*)d_in[7];
    const float* b0    = (const float*)d_in[8];
    const float* We1   = (const float*)d_in[9];
    const float* be1   = (const float*)d_in[10];
    const float* We2   = (const float*)d_in[11];
    const float* be2   = (const float*)d_in[12];
    const float* Wroot = (const float*)d_in[13];
    const float* bconv = (const float*)d_in[14];
    const float* gwih  = (const float*)d_in[15];
    const float* gwhh  = (const float*)d_in[16];
    const float* gbih  = (const float*)d_in[17];
    const float* gbhh  = (const float*)d_in[18];
    const float* lwih  = (const float*)d_in[19];
    const float* lwhh  = (const float*)d_in[20];
    const float* lbih  = (const float*)d_in[21];
    const float* lbhh  = (const float*)d_in[22];
    const float* W1    = (const float*)d_in[23];
    const float* b1    = (const float*)d_in[24];
    const float* W2    = (const float*)d_in[25];
    const float* b2    = (const float*)d_in[26];
    const float* W3    = (const float*)d_in[27];
    const float* b3    = (const float*)d_in[28];
    float* y = (float*)d_out;

    char* ws = (char*)d_ws;
    size_t off = 0;
    auto alloc = [&](size_t nbytes) {
        void* ptr = (void*)(ws + off);
        off += align_up(nbytes, 256);
        return ptr;
    };
    float* hbuf   = (float*)alloc((size_t)N_NODES * 64 * 4);
    float* reb    = (float*)alloc((size_t)N_EDGES * 64 * 4);
    float* msgA   = (float*)alloc((size_t)N_EDGES * 64 * 4);
    float* msgB   = (float*)alloc((size_t)N_EDGES * 64 * 4);
    short* We2b   = (short*)alloc((size_t)65 * 4096 * 2);
    short* WB1h   = (short*)alloc(16384 * 2);
    short* WB1l   = (short*)alloc(16384 * 2);
    short* WB2h   = (short*)alloc(12288 * 2);
    short* WB2l   = (short*)alloc(12288 * 2);
    float* lwihT  = (float*)alloc(32768 * 4);
    float* lwhhT  = (float*)alloc(16384 * 4);
    int*   offs   = (int*)  alloc((NB + 1) * 4);
    int*   deg    = (int*)  alloc(N_NODES * 4);
    int*   rowptr = (int*)  alloc((N_NODES + 1) * 4);
    int*   cursor = (int*)  alloc(N_NODES * 4);
    int*   perm   = (int*)  alloc(N_EDGES * 4);

    // ---- prep (fused) + CSR ----
    k_prep<<<1349, 256, 0, stream>>>(We2, be2, We2b, Wroot, gwhh, gwih,
                                     WB1h, WB1l, WB2h, WB2l,
                                     lwih, lwhh, lwihT, lwhhT, batch, offs);
    hipMemsetAsync(deg, 0, (size_t)N_NODES * 4, stream);
    k_count<<<(N_EDGES + 255) / 256, 256, 0, stream>>>(ei, deg);
    k_scan<<<1, 1024, 0, stream>>>(deg, rowptr, cursor);
    k_fill<<<(N_EDGES + 255) / 256, 256, 0, stream>>>(ei, cursor, perm);

    // ---- encoder (fused) ----
    k_init_feat<<<17500, 256, 0, stream>>>(x, W0, b0, hbuf, ea, We1, be1, reb);

    // ---- 4 message-passing + GRU iterations ----
    int tiles = (N_EDGES + 63) / 64;
    for (int it = 0; it < 4; ++it) {
        k_msg_mfma<<<tiles * 2, 256, 0, stream>>>(hbuf, reb, We2b, ei, msgA, msgB);
        k_node_update<<<N_NODES / 32, 256, 0, stream>>>(hbuf, msgA, msgB, rowptr, perm,
                                                        WB1h, WB1l, WB2h, WB2l,
                                                        bconv, gbih, gbhh);
    }

    // ---- fused Set2Set (3 iters) + readout ----
    k_set2set<<<NB, 256, 0, stream>>>(hbuf, offs, t, p, lwihT, lwhhT, lbih, lbhh,
                                      W1, b1, W2, b2, W3, b3, y);
}

// Round 14
// 415.781 us; speedup vs baseline: 1.7911x; 1.1289x over previous
//
#include <hip/hip_runtime.h>
#include <math.h>

#define N_NODES 20000
#define N_EDGES 50000
#define NB      1024
#define IND     32
#define HDIM    64

typedef __attribute__((ext_vector_type(8))) short bf16x8;
typedef __attribute__((ext_vector_type(4))) float f32x4;

static inline size_t align_up(size_t x, size_t a) { return (x + a - 1) & ~(a - 1); }

__device__ __forceinline__ float sigmoidf_(float x) {
    return 1.0f / (1.0f + __expf(-x));
}
__device__ __forceinline__ float tanhf_(float x) {
    float xc = fminf(fmaxf(x, -15.0f), 15.0f);
    float e = __expf(2.0f * xc);
    return (e - 1.0f) / (e + 1.0f);
}
__device__ __forceinline__ unsigned pk2(float p0, float p1) {
    unsigned u0 = __float_as_uint(p0) + 0x8000u;
    unsigned u1 = __float_as_uint(p1) + 0x8000u;
    return __builtin_amdgcn_perm(u1, u0, 0x07060302u);
}
__device__ __forceinline__ unsigned bf1(float v) {
    return (__float_as_uint(v) + 0x8000u) >> 16;
}

// ---- mega-prep: We2b permute + wsplit + LSTM transposes + offsets + node_init + edge_feat ----
// grid = 1040 + 112 + 128 + 64 + 5 (=1349) + 5000 (node) + 12500 (edge) = 18849
__global__ void k_prep(const float* __restrict__ We2, const float* __restrict__ be2,
                       short* __restrict__ We2b,
                       const float* __restrict__ Wroot, const float* __restrict__ gwhh,
                       const float* __restrict__ gwih,
                       short* __restrict__ WB1h, short* __restrict__ WB1l,
                       short* __restrict__ WB2h, short* __restrict__ WB2l,
                       const float* __restrict__ lwih, const float* __restrict__ lwhh,
                       float* __restrict__ lwihT, float* __restrict__ lwhhT,
                       const int* __restrict__ batch, int* __restrict__ offs,
                       const float* __restrict__ x, const float* __restrict__ W0,
                       const float* __restrict__ b0, float* __restrict__ hbuf,
                       const float* __restrict__ ea, const float* __restrict__ We1,
                       const float* __restrict__ be1, float* __restrict__ re) {
    int bid = blockIdx.x, tid = threadIdx.x;
    if (bid < 1040) {
        int idx = bid * 256 + tid;                 // 0 .. 65*4096-1
        int s = idx >> 12;
        int col = idx & 4095;
        int k = col >> 6, o = col & 63;
        float val = (s < 64) ? We2[k * 4096 + s * 64 + o] : be2[k * 64 + o];
        int dst = s * 4096 + (((o >> 4) * 128 + (k >> 5) * 64 + ((k >> 3) & 3) * 16 + (o & 15)) << 3) + (k & 7);
        We2b[dst] = (short)bf1(val);
    } else if (bid < 1152) {
        int idx = (bid - 1040) * 256 + tid;
        if (idx < 28672) {
            bool b1 = idx < 16384;
            int li = b1 ? idx : idx - 16384;
            int j = li & 7, lane = (li >> 3) & 63, c = (li >> 9) & 1, otile = li >> 10;
            int k = c * 32 + (lane >> 4) * 8 + j;
            int o = otile * 16 + (lane & 15);
            float val;
            if (b1) val = (o < 64) ? Wroot[k * 64 + o] : gwhh[(o - 64) * 64 + k];
            else    val = gwih[o * 64 + k];
            unsigned hs = bf1(val);
            float lo = val - __uint_as_float(hs << 16);
            unsigned ls = bf1(lo);
            if (b1) { WB1h[li] = (short)hs; WB1l[li] = (short)ls; }
            else    { WB2h[li] = (short)hs; WB2l[li] = (short)ls; }
        }
    } else if (bid < 1280) {
        int idx = (bid - 1152) * 256 + tid;        // < 32768 : lwihT[i*256+j] = lwih[j*128+i]
        int i = idx >> 8, j = idx & 255;
        lwihT[idx] = lwih[j * 128 + i];
    } else if (bid < 1344) {
        int idx = (bid - 1280) * 256 + tid;        // < 16384 : lwhhT[i*256+j] = lwhh[j*64+i]
        int i = idx >> 8, j = idx & 255;
        lwhhT[idx] = lwhh[j * 64 + i];
    } else if (bid < 1349) {
        int i = (bid - 1344) * 256 + tid;
        if (i <= NB) {
            int lo = 0, hi = N_NODES;
            while (lo < hi) { int mid = (lo + hi) >> 1; if (batch[mid] < i) lo = mid + 1; else hi = mid; }
            offs[i] = lo;
        }
    } else if (bid < 6349) {
        int w = tid >> 6, j = tid & 63;
        int n = (bid - 1349) * 4 + w;
        float acc = b0[j];
        const float* xr = x + n * IND;
#pragma unroll
        for (int i = 0; i < IND; ++i) acc = fmaf(xr[i], W0[i * 64 + j], acc);
        hbuf[n * 64 + j] = fmaxf(acc, 0.0f);
    } else {
        int w = tid >> 6, j = tid & 63;
        int e = (bid - 6349) * 4 + w;
        if (e < N_EDGES) {
            float acc = be1[j];
            const float* er = ea + e * 6;
#pragma unroll
            for (int i = 0; i < 6; ++i) acc = fmaf(er[i], We1[i * 64 + j], acc);
            re[e * 64 + j] = fmaxf(acc, 0.0f);
        }
    }
}

// ---- CSR build ----
__global__ void k_count(const int* __restrict__ ei, int* __restrict__ deg) {
    int e = blockIdx.x * 256 + threadIdx.x;
    if (e < N_EDGES) atomicAdd(&deg[ei[N_EDGES + e]], 1);
}

__global__ void k_scan(const int* __restrict__ deg, int* __restrict__ rowptr, int* __restrict__ cursor) {
    __shared__ int s_w[16];
    int t = threadIdx.x;
    int base = t * 20;
    int v[20]; int s = 0;
#pragma unroll
    for (int i = 0; i < 20; ++i) {
        int idx = base + i;
        v[i] = (idx < N_NODES) ? deg[idx] : 0;
        s += v[i];
    }
    int lane = t & 63, w = t >> 6;
    int inc = s;
#pragma unroll
    for (int off = 1; off < 64; off <<= 1) {
        int o = __shfl_up(inc, off);
        if (lane >= off) inc += o;
    }
    if (lane == 63) s_w[w] = inc;
    __syncthreads();
    if (w == 0 && lane < 16) {
        int x = s_w[lane];
        int xs = x;
#pragma unroll
        for (int off = 1; off < 16; off <<= 1) {
            int o = __shfl_up(xs, off);
            if (lane >= off) xs += o;
        }
        s_w[lane] = xs - x;
    }
    __syncthreads();
    int run = s_w[w] + (inc - s);
#pragma unroll
    for (int i = 0; i < 20; ++i) {
        int idx = base + i;
        if (idx < N_NODES) { rowptr[idx] = run; cursor[idx] = run; }
        else if (idx == N_NODES) rowptr[idx] = run;
        run += v[i];
    }
}

__global__ void k_fill(const int* __restrict__ ei, int* __restrict__ cursor, int* __restrict__ perm) {
    int e = blockIdx.x * 256 + threadIdx.x;
    if (e < N_EDGES) {
        int pos = atomicAdd(&cursor[ei[N_EDGES + e]], 1);
        perm[pos] = e;
    }
}

// msg kernel — R5/R10 verified structure: 64 edges/block, 256 threads, (256,3), VGPR ~84.
__launch_bounds__(256, 3)
__global__ void k_msg_mfma(const float* __restrict__ hbuf, const float* __restrict__ reb,
                           const short* __restrict__ We2b, const int* __restrict__ ei,
                           float* __restrict__ msg) {
    __shared__ float s_v[64][64];    // [h][e]
    int tid = threadIdx.x;
    int eb = blockIdx.x * 64;
    int lane = tid & 63;
    int w = tid >> 6;
    int l15 = lane & 15, lhi = lane >> 4;

    // stage s_v transposed
    {
        int se = tid >> 2;
        int sh = tid & 3;
        int ge = eb + se;
        const float* rowp = (ge < N_EDGES) ? (hbuf + (size_t)ei[ge] * 64) : (const float*)0;
#pragma unroll
        for (int rr4 = 0; rr4 < 4; ++rr4) {
            int hb = rr4 * 16 + sh * 4;
            float4 vv = rowp ? *(const float4*)(rowp + hb) : make_float4(0.f, 0.f, 0.f, 0.f);
            s_v[hb + 0][se] = vv.x; s_v[hb + 1][se] = vv.y;
            s_v[hb + 2][se] = vv.z; s_v[hb + 3][se] = vv.w;
        }
    }

    // pack re A-fragments once
    union U { int4 i4; bf16x8 v; };
    U a_re[4][2];
#pragma unroll
    for (int m = 0; m < 4; ++m) {
        int ge = eb + m * 16 + l15;
        if (ge < N_EDGES) {
            const float* rp = reb + (size_t)ge * 64 + lhi * 8;
            float4 x0 = *(const float4*)(rp);
            float4 x1 = *(const float4*)(rp + 4);
            float4 y0 = *(const float4*)(rp + 32);
            float4 y1 = *(const float4*)(rp + 36);
            a_re[m][0].i4 = make_int4(pk2(x0.x, x0.y), pk2(x0.z, x0.w), pk2(x1.x, x1.y), pk2(x1.z, x1.w));
            a_re[m][1].i4 = make_int4(pk2(y0.x, y0.y), pk2(y0.z, y0.w), pk2(y1.x, y1.y), pk2(y1.z, y1.w));
        } else {
            a_re[m][0].i4 = make_int4(0, 0, 0, 0);
            a_re[m][1].i4 = make_int4(0, 0, 0, 0);
        }
    }

    // B prefetch: 4 rotating register sets, depth 4
    const int4* bp0 = (const int4*)We2b + (w * 128 + lane);   // slab stride = 512 int4
    const int4* bp1 = bp0 + 64;
    int4 Sc0[4], Sc1[4];
#pragma unroll
    for (int j = 0; j < 4; ++j) {
        Sc0[j] = bp0[j * 512];
        Sc1[j] = bp1[j * 512];
    }

    __syncthreads();

    const f32x4 zero4 = {0.f, 0.f, 0.f, 0.f};
    f32x4 macc[4];
#pragma unroll
    for (int m = 0; m < 4; ++m) macc[m] = zero4;

    // v prefetch depth 1
    float4 vv[4], vn[4];
#pragma unroll
    for (int m = 0; m < 4; ++m) vv[m] = *(const float4*)&s_v[0][m * 16 + lhi * 4];

    for (int g = 0; g < 16; ++g) {
#pragma unroll
        for (int j = 0; j < 4; ++j) {
            int s = g * 4 + j;
            int snext = (s < 63) ? (s + 1) : 63;
#pragma unroll
            for (int m = 0; m < 4; ++m)
                vn[m] = *(const float4*)&s_v[snext][m * 16 + lhi * 4];
            U bb0, bb1; bb0.i4 = Sc0[j]; bb1.i4 = Sc1[j];
#pragma unroll
            for (int m = 0; m < 4; ++m) {
                f32x4 t = __builtin_amdgcn_mfma_f32_16x16x32_bf16(a_re[m][0].v, bb0.v, zero4, 0, 0, 0);
                t = __builtin_amdgcn_mfma_f32_16x16x32_bf16(a_re[m][1].v, bb1.v, t, 0, 0, 0);
                macc[m][0] = fmaf(vv[m].x, t[0], macc[m][0]);
                macc[m][1] = fmaf(vv[m].y, t[1], macc[m][1]);
                macc[m][2] = fmaf(vv[m].z, t[2], macc[m][2]);
                macc[m][3] = fmaf(vv[m].w, t[3], macc[m][3]);
            }
            int sload = (s + 4 <= 64) ? (s + 4) : 64;
            Sc0[j] = bp0[sload * 512];
            Sc1[j] = bp1[sload * 512];
#pragma unroll
            for (int m = 0; m < 4; ++m) vv[m] = vn[m];
        }
    }

    // bias slab (set 0 holds slab 64): msg += v @ be2
    {
        U bb0, bb1; bb0.i4 = Sc0[0]; bb1.i4 = Sc1[0];
#pragma unroll
        for (int m = 0; m < 4; ++m) {
            int e = m * 16 + l15;
            U a0, a1;
            a0.i4 = make_int4(
                pk2(s_v[lhi * 8 + 0][e], s_v[lhi * 8 + 1][e]),
                pk2(s_v[lhi * 8 + 2][e], s_v[lhi * 8 + 3][e]),
                pk2(s_v[lhi * 8 + 4][e], s_v[lhi * 8 + 5][e]),
                pk2(s_v[lhi * 8 + 6][e], s_v[lhi * 8 + 7][e]));
            a1.i4 = make_int4(
                pk2(s_v[32 + lhi * 8 + 0][e], s_v[32 + lhi * 8 + 1][e]),
                pk2(s_v[32 + lhi * 8 + 2][e], s_v[32 + lhi * 8 + 3][e]),
                pk2(s_v[32 + lhi * 8 + 4][e], s_v[32 + lhi * 8 + 5][e]),
                pk2(s_v[32 + lhi * 8 + 6][e], s_v[32 + lhi * 8 + 7][e]));
            macc[m] = __builtin_amdgcn_mfma_f32_16x16x32_bf16(a0.v, bb0.v, macc[m], 0, 0, 0);
            macc[m] = __builtin_amdgcn_mfma_f32_16x16x32_bf16(a1.v, bb1.v, macc[m], 0, 0, 0);
        }
    }
    int o = w * 16 + l15;
#pragma unroll
    for (int m = 0; m < 4; ++m) {
#pragma unroll
        for (int r = 0; r < 4; ++r) {
            int el = m * 16 + lhi * 4 + r;
            int ge = eb + el;
            if (ge < N_EDGES) msg[(size_t)ge * 64 + o] = macc[m][r];
        }
    }
}

// MFMA node update: conv + GRU with split-bf16 weights. 32 nodes / block (625 blocks).
__launch_bounds__(256, 4)
__global__ void k_node_update(float* __restrict__ hbuf, const float* __restrict__ msg,
                              const int* __restrict__ rowptr, const int* __restrict__ perm,
                              const short* __restrict__ WB1h, const short* __restrict__ WB1l,
                              const short* __restrict__ WB2h, const short* __restrict__ WB2l,
                              const float* __restrict__ bconv, const float* __restrict__ bih,
                              const float* __restrict__ bhh) {
    __shared__ short s_hh[32][72];
    __shared__ short s_hl[32][72];
    __shared__ short s_mh[32][72];
    __shared__ short s_ml[32][72];
    __shared__ float s_agg[32][68];
    int tid = threadIdx.x;
    int nbase = blockIdx.x * 32;
    int lane = tid & 63, w = tid >> 6;
    int l15 = lane & 15, lhi = lane >> 4;

    {
        int nt = tid >> 3, q = tid & 7;
        int n = nbase + nt;
#pragma unroll
        for (int c4 = 0; c4 < 2; ++c4) {
            int col = q * 8 + c4 * 4;
            float4 v = *(const float4*)&hbuf[(size_t)n * 64 + col];
            unsigned h01 = pk2(v.x, v.y), h23 = pk2(v.z, v.w);
            float f0 = __uint_as_float(h01 << 16);
            float f1 = __uint_as_float(h01 & 0xffff0000u);
            float f2 = __uint_as_float(h23 << 16);
            float f3 = __uint_as_float(h23 & 0xffff0000u);
            unsigned l01 = pk2(v.x - f0, v.y - f1), l23 = pk2(v.z - f2, v.w - f3);
            *(unsigned*)&s_hh[nt][col]     = h01;
            *(unsigned*)&s_hh[nt][col + 2] = h23;
            *(unsigned*)&s_hl[nt][col]     = l01;
            *(unsigned*)&s_hl[nt][col + 2] = l23;
        }
        float4 aggv[2];
#pragma unroll
        for (int c4 = 0; c4 < 2; ++c4)
            aggv[c4] = *(const float4*)&bconv[q * 8 + c4 * 4];
        int rs = rowptr[n], rend = rowptr[n + 1];
        for (int qq = rs; qq < rend; ++qq) {
            const float* mrow = msg + (size_t)perm[qq] * 64 + q * 8;
#pragma unroll
            for (int c4 = 0; c4 < 2; ++c4) {
                float4 mv = *(const float4*)&mrow[c4 * 4];
                aggv[c4].x += mv.x; aggv[c4].y += mv.y;
                aggv[c4].z += mv.z; aggv[c4].w += mv.w;
            }
        }
#pragma unroll
        for (int c4 = 0; c4 < 2; ++c4)
            *(float4*)&s_agg[nt][q * 8 + c4 * 4] = aggv[c4];
    }
    __syncthreads();

    union U { int4 i4; bf16x8 v; };
    U ah[2][2], al[2][2];
#pragma unroll
    for (int m = 0; m < 2; ++m)
#pragma unroll
        for (int c = 0; c < 2; ++c) {
            ah[m][c].i4 = *(const int4*)&s_hh[m * 16 + l15][c * 32 + lhi * 8];
            al[m][c].i4 = *(const int4*)&s_hl[m * 16 + l15][c * 32 + lhi * 8];
        }

    const int4* B1h = (const int4*)WB1h;
    const int4* B1l = (const int4*)WB1l;
    const int4* B2h = (const int4*)WB2h;
    const int4* B2l = (const int4*)WB2l;

    f32x4 C0[2], G[3][2], I[3][2];

    {
        int ot = w;
        U bh0, bh1, bl0, bl1;
        bh0.i4 = B1h[(ot * 2 + 0) * 64 + lane];
        bh1.i4 = B1h[(ot * 2 + 1) * 64 + lane];
        bl0.i4 = B1l[(ot * 2 + 0) * 64 + lane];
        bl1.i4 = B1l[(ot * 2 + 1) * 64 + lane];
#pragma unroll
        for (int m = 0; m < 2; ++m) {
            f32x4 c;
#pragma unroll
            for (int r = 0; r < 4; ++r) c[r] = s_agg[m * 16 + lhi * 4 + r][w * 16 + l15];
            c = __builtin_amdgcn_mfma_f32_16x16x32_bf16(ah[m][0].v, bh0.v, c, 0, 0, 0);
            c = __builtin_amdgcn_mfma_f32_16x16x32_bf16(ah[m][1].v, bh1.v, c, 0, 0, 0);
            c = __builtin_amdgcn_mfma_f32_16x16x32_bf16(al[m][0].v, bh0.v, c, 0, 0, 0);
            c = __builtin_amdgcn_mfma_f32_16x16x32_bf16(al[m][1].v, bh1.v, c, 0, 0, 0);
            c = __builtin_amdgcn_mfma_f32_16x16x32_bf16(ah[m][0].v, bl0.v, c, 0, 0, 0);
            c = __builtin_amdgcn_mfma_f32_16x16x32_bf16(ah[m][1].v, bl1.v, c, 0, 0, 0);
            C0[m] = c;
        }
    }
#pragma unroll
    for (int m = 0; m < 2; ++m)
#pragma unroll
        for (int r = 0; r < 4; ++r) {
            float mv = fmaxf(C0[m][r], 0.0f);
            int row = m * 16 + lhi * 4 + r, col = w * 16 + l15;
            unsigned hs = bf1(mv);
            float lof = mv - __uint_as_float(hs << 16);
            s_mh[row][col] = (short)hs;
            s_ml[row][col] = (short)bf1(lof);
        }
#pragma unroll
    for (int p = 1; p < 4; ++p) {
        int ot = p * 4 + w;
        U bh0, bh1, bl0, bl1;
        bh0.i4 = B1h[(ot * 2 + 0) * 64 + lane];
        bh1.i4 = B1h[(ot * 2 + 1) * 64 + lane];
        bl0.i4 = B1l[(ot * 2 + 0) * 64 + lane];
        bl1.i4 = B1l[(ot * 2 + 1) * 64 + lane];
        float bv = bhh[(p - 1) * 64 + w * 16 + l15];
#pragma unroll
        for (int m = 0; m < 2; ++m) {
            f32x4 c = {bv, bv, bv, bv};
            c = __builtin_amdgcn_mfma_f32_16x16x32_bf16(ah[m][0].v, bh0.v, c, 0, 0, 0);
            c = __builtin_amdgcn_mfma_f32_16x16x32_bf16(ah[m][1].v, bh1.v, c, 0, 0, 0);
            c = __builtin_amdgcn_mfma_f32_16x16x32_bf16(al[m][0].v, bh0.v, c, 0, 0, 0);
            c = __builtin_amdgcn_mfma_f32_16x16x32_bf16(al[m][1].v, bh1.v, c, 0, 0, 0);
            c = __builtin_amdgcn_mfma_f32_16x16x32_bf16(ah[m][0].v, bl0.v, c, 0, 0, 0);
            c = __builtin_amdgcn_mfma_f32_16x16x32_bf16(ah[m][1].v, bl1.v, c, 0, 0, 0);
            G[p - 1][m] = c;
        }
    }
    __syncthreads();
    U mh[2][2], ml[2][2];
#pragma unroll
    for (int m = 0; m < 2; ++m)
#pragma unroll
        for (int c = 0; c < 2; ++c) {
            mh[m][c].i4 = *(const int4*)&s_mh[m * 16 + l15][c * 32 + lhi * 8];
            ml[m][c].i4 = *(const int4*)&s_ml[m * 16 + l15][c * 32 + lhi * 8];
        }
#pragma unroll
    for (int p = 0; p < 3; ++p) {
        int ot = p * 4 + w;
        U bh0, bh1, bl0, bl1;
        bh0.i4 = B2h[(ot * 2 + 0) * 64 + lane];
        bh1.i4 = B2h[(ot * 2 + 1) * 64 + lane];
        bl0.i4 = B2l[(ot * 2 + 0) * 64 + lane];
        bl1.i4 = B2l[(ot * 2 + 1) * 64 + lane];
        float bv = bih[p * 64 + w * 16 + l15];
#pragma unroll
        for (int m = 0; m < 2; ++m) {
            f32x4 c = {bv, bv, bv, bv};
            c = __builtin_amdgcn_mfma_f32_16x16x32_bf16(mh[m][0].v, bh0.v, c, 0, 0, 0);
            c = __builtin_amdgcn_mfma_f32_16x16x32_bf16(mh[m][1].v, bh1.v, c, 0, 0, 0);
            c = __builtin_amdgcn_mfma_f32_16x16x32_bf16(ml[m][0].v, bh0.v, c, 0, 0, 0);
            c = __builtin_amdgcn_mfma_f32_16x16x32_bf16(ml[m][1].v, bh1.v, c, 0, 0, 0);
            c = __builtin_amdgcn_mfma_f32_16x16x32_bf16(mh[m][0].v, bl0.v, c, 0, 0, 0);
            c = __builtin_amdgcn_mfma_f32_16x16x32_bf16(mh[m][1].v, bl1.v, c, 0, 0, 0);
            I[p][m] = c;
        }
    }
#pragma unroll
    for (int m = 0; m < 2; ++m)
#pragma unroll
        for (int r = 0; r < 4; ++r) {
            int row = m * 16 + lhi * 4 + r;
            int n = nbase + row;
            int col = w * 16 + l15;
            float hold = __uint_as_float(((unsigned)(unsigned short)s_hh[row][col]) << 16)
                       + __uint_as_float(((unsigned)(unsigned short)s_hl[row][col]) << 16);
            float rg = sigmoidf_(I[0][m][r] + G[0][m][r]);
            float z  = sigmoidf_(I[1][m][r] + G[1][m][r]);
            float nn = tanhf_(I[2][m][r] + rg * G[2][m][r]);
            hbuf[(size_t)n * 64 + col] = (1.0f - z) * nn + z * hold;
        }
}

// Fused Set2Set (3 iterations) + readout MLP. 256 threads (4 waves) per graph.
__launch_bounds__(256)
__global__ void k_set2set(const float* __restrict__ hbuf, const int* __restrict__ offs,
                          const float* __restrict__ t, const float* __restrict__ p,
                          const float* __restrict__ lwihT, const float* __restrict__ lwhhT,
                          const float* __restrict__ l_bih, const float* __restrict__ l_bhh,
                          const float* __restrict__ W1, const float* __restrict__ b1,
                          const float* __restrict__ W2, const float* __restrict__ b2,
                          const float* __restrict__ W3, const float* __restrict__ b3,
                          float* __restrict__ y) {
    __shared__ float s_qs[192];       // [0..127]=q_star, [128..191]=qh
    __shared__ float s_g[256];
    __shared__ float s_racc[4][64];
    __shared__ float s_m[4], s_l[4];
    __shared__ float s_y[64];
    int b = blockIdx.x;
    int tid = threadIdx.x;
    int w = tid >> 6, lane = tid & 63;
    int s = offs[b], e = offs[b + 1];
    float bi = l_bih[tid] + l_bhh[tid];
    float qc = 0.f;                   // live in wave-0 lanes

    if (tid < 192) s_qs[tid] = 0.f;
    __syncthreads();

    for (int iter = 0; iter < 3; ++iter) {
        // ---- gates: 256 outputs, one per thread ----
        float g = bi;
#pragma unroll 8
        for (int i = 0; i < 128; ++i) g = fmaf(s_qs[i], lwihT[i * 256 + tid], g);
#pragma unroll 8
        for (int i = 0; i < 64; ++i)  g = fmaf(s_qs[128 + i], lwhhT[i * 256 + tid], g);
        s_g[tid] = g;
        __syncthreads();
        // ---- LSTM cell update (wave 0) ----
        if (w == 0) {
            float ci = sigmoidf_(s_g[lane]);
            float cf = sigmoidf_(s_g[64 + lane]);
            float cg = tanhf_(s_g[128 + lane]);
            float co = sigmoidf_(s_g[192 + lane]);
            qc = cf * qc + ci * cg;
            float qh = co * tanhf_(qc);
            s_qs[lane] = qh;          // q (first half of q_star)
            s_qs[128 + lane] = qh;    // qh state
        }
        __syncthreads();
        // ---- attention: nodes round-robin across 4 waves ----
        float qv = s_qs[128 + lane];
        float mx = -1e30f, l = 0.0f, racc = 0.0f;
        for (int n = s + w; n < e; n += 4) {
            float xv = hbuf[(size_t)n * 64 + lane];
            float prod = xv * qv;
#pragma unroll
            for (int off = 32; off > 0; off >>= 1) prod += __shfl_xor(prod, off);
            float mnew = fmaxf(mx, prod);
            float scale = __expf(mx - mnew);
            float wgt = __expf(prod - mnew);
            l = l * scale + wgt;
            racc = racc * scale + wgt * xv;
            mx = mnew;
        }
        s_racc[w][lane] = racc;
        if (lane == 0) { s_m[w] = mx; s_l[w] = l; }
        __syncthreads();
        // ---- merge partials (wave 0) ----
        if (w == 0) {
            float M = fmaxf(fmaxf(s_m[0], s_m[1]), fmaxf(s_m[2], s_m[3]));
            float L = 0.f, R = 0.f;
#pragma unroll
            for (int ww = 0; ww < 4; ++ww) {
                float sc = __expf(s_m[ww] - M);
                L += s_l[ww] * sc;
                R = fmaf(s_racc[ww][lane], sc, R);
            }
            s_qs[64 + lane] = (e > s) ? (R / L) : 0.0f;
        }
        __syncthreads();
    }
    // ---- readout (wave 0) ----
    if (w == 0) {
        float acc = b1[lane];
#pragma unroll 8
        for (int i = 0; i < 128; ++i) acc = fmaf(s_qs[i], W1[i * 64 + lane], acc);
        acc = fmaf(t[b], W1[128 * 64 + lane], acc);
        acc = fmaf(p[b], W1[129 * 64 + lane], acc);
        acc = fmaxf(acc, 0.0f);
        s_y[lane] = acc;
        float acc2 = b2[lane];
#pragma unroll 8
        for (int i = 0; i < 64; ++i) acc2 = fmaf(s_y[i], W2[i * 64 + lane], acc2);
        acc2 = fmaxf(acc2, 0.0f);
        float part = acc2 * W3[lane];
#pragma unroll
        for (int off = 32; off > 0; off >>= 1) part += __shfl_xor(part, off);
        if (lane == 0) y[b] = part + b3[0];
    }
}

extern "C" void kernel_launch(void* const* d_in, const int* in_sizes, int n_in,
                              void* d_out, int out_size, void* d_ws, size_t ws_size,
                              hipStream_t stream) {
    const float* x     = (const float*)d_in[0];
    const int*   ei    = (const int*)  d_in[1];
    const float* ea    = (const float*)d_in[2];
    const int*   batch = (const int*)  d_in[3];
    const float* t     = (const float*)d_in[4];
    const float* p     = (const float*)d_in[5];
    const float* W0    = (const float*)d_in[7];
    const float* b0    = (const float*)d_in[8];
    const float* We1   = (const float*)d_in[9];
    const float* be1   = (const float*)d_in[10];
    const float* We2   = (const float*)d_in[11];
    const float* be2   = (const float*)d_in[12];
    const float* Wroot = (const float*)d_in[13];
    const float* bconv = (const float*)d_in[14];
    const float* gwih  = (const float*)d_in[15];
    const float* gwhh  = (const float*)d_in[16];
    const float* gbih  = (const float*)d_in[17];
    const float* gbhh  = (const float*)d_in[18];
    const float* lwih  = (const float*)d_in[19];
    const float* lwhh  = (const float*)d_in[20];
    const float* lbih  = (const float*)d_in[21];
    const float* lbhh  = (const float*)d_in[22];
    const float* W1    = (const float*)d_in[23];
    const float* b1    = (const float*)d_in[24];
    const float* W2    = (const float*)d_in[25];
    const float* b2    = (const float*)d_in[26];
    const float* W3    = (const float*)d_in[27];
    const float* b3    = (const float*)d_in[28];
    float* y = (float*)d_out;

    char* ws = (char*)d_ws;
    size_t off = 0;
    auto alloc = [&](size_t nbytes) {
        void* ptr = (void*)(ws + off);
        off += align_up(nbytes, 256);
        return ptr;
    };
    float* hbuf   = (float*)alloc((size_t)N_NODES * 64 * 4);
    float* reb    = (float*)alloc((size_t)N_EDGES * 64 * 4);
    float* msg    = (float*)alloc((size_t)N_EDGES * 64 * 4);
    short* We2b   = (short*)alloc((size_t)65 * 4096 * 2);
    short* WB1h   = (short*)alloc(16384 * 2);
    short* WB1l   = (short*)alloc(16384 * 2);
    short* WB2h   = (short*)alloc(12288 * 2);
    short* WB2l   = (short*)alloc(12288 * 2);
    float* lwihT  = (float*)alloc(32768 * 4);
    float* lwhhT  = (float*)alloc(16384 * 4);
    int*   offs   = (int*)  alloc((NB + 1) * 4);
    int*   deg    = (int*)  alloc(N_NODES * 4);
    int*   rowptr = (int*)  alloc((N_NODES + 1) * 4);
    int*   cursor = (int*)  alloc(N_NODES * 4);
    int*   perm   = (int*)  alloc(N_EDGES * 4);

    // ---- mega-prep (prep + encoder) + CSR ----
    k_prep<<<18849, 256, 0, stream>>>(We2, be2, We2b, Wroot, gwhh, gwih,
                                      WB1h, WB1l, WB2h, WB2l,
                                      lwih, lwhh, lwihT, lwhhT, batch, offs,
                                      x, W0, b0, hbuf, ea, We1, be1, reb);
    hipMemsetAsync(deg, 0, (size_t)N_NODES * 4, stream);
    k_count<<<(N_EDGES + 255) / 256, 256, 0, stream>>>(ei, deg);
    k_scan<<<1, 1024, 0, stream>>>(deg, rowptr, cursor);
    k_fill<<<(N_EDGES + 255) / 256, 256, 0, stream>>>(ei, cursor, perm);

    // ---- 4 message-passing + GRU iterations ----
    for (int it = 0; it < 4; ++it) {
        k_msg_mfma<<<(N_EDGES + 63) / 64, 256, 0, stream>>>(hbuf, reb, We2b, ei, msg);
        k_node_update<<<N_NODES / 32, 256, 0, stream>>>(hbuf, msg, rowptr, perm,
                                                        WB1h, WB1l, WB2h, WB2l,
                                                        bconv, gbih, gbhh);
    }

    // ---- fused Set2Set (3 iters) + readout ----
    k_set2set<<<NB, 256, 0, stream>>>(hbuf, offs, t, p, lwihT, lwhhT, lbih, lbhh,
                                      W1, b1, W2, b2, W3, b3, y);
}

// Round 15
// 413.967 us; speedup vs baseline: 1.7989x; 1.0044x over previous
//
#include <hip/hip_runtime.h>
#include <math.h>

#define N_NODES 20000
#define N_EDGES 50000
#define NB      1024
#define IND     32
#define HDIM    64

typedef __attribute__((ext_vector_type(8))) short bf16x8;
typedef __attribute__((ext_vector_type(4))) float f32x4;

static inline size_t align_up(size_t x, size_t a) { return (x + a - 1) & ~(a - 1); }

__device__ __forceinline__ float sigmoidf_(float x) {
    return 1.0f / (1.0f + __expf(-x));
}
__device__ __forceinline__ float tanhf_(float x) {
    float xc = fminf(fmaxf(x, -15.0f), 15.0f);
    float e = __expf(2.0f * xc);
    return (e - 1.0f) / (e + 1.0f);
}
__device__ __forceinline__ unsigned pk2(float p0, float p1) {
    unsigned u0 = __float_as_uint(p0) + 0x8000u;
    unsigned u1 = __float_as_uint(p1) + 0x8000u;
    return __builtin_amdgcn_perm(u1, u0, 0x07060302u);
}
__device__ __forceinline__ unsigned bf1(float v) {
    return (__float_as_uint(v) + 0x8000u) >> 16;
}

// ---- mega-prep: We2b permute + wsplit + LSTM transposes + offsets + node_init +
//      edge_feat + edge degree count (deg pre-zeroed by memset BEFORE this kernel) ----
// grid = 1040 + 112 + 128 + 64 + 5 (=1349) + 5000 (node) + 12500 (edge) + 196 (count) = 19045
__global__ void k_prep(const float* __restrict__ We2, const float* __restrict__ be2,
                       short* __restrict__ We2b,
                       const float* __restrict__ Wroot, const float* __restrict__ gwhh,
                       const float* __restrict__ gwih,
                       short* __restrict__ WB1h, short* __restrict__ WB1l,
                       short* __restrict__ WB2h, short* __restrict__ WB2l,
                       const float* __restrict__ lwih, const float* __restrict__ lwhh,
                       float* __restrict__ lwihT, float* __restrict__ lwhhT,
                       const int* __restrict__ batch, int* __restrict__ offs,
                       const float* __restrict__ x, const float* __restrict__ W0,
                       const float* __restrict__ b0, float* __restrict__ hbuf,
                       const float* __restrict__ ea, const float* __restrict__ We1,
                       const float* __restrict__ be1, float* __restrict__ re,
                       const int* __restrict__ ei, int* __restrict__ deg) {
    int bid = blockIdx.x, tid = threadIdx.x;
    if (bid < 1040) {
        int idx = bid * 256 + tid;                 // 0 .. 65*4096-1
        int s = idx >> 12;
        int col = idx & 4095;
        int k = col >> 6, o = col & 63;
        float val = (s < 64) ? We2[k * 4096 + s * 64 + o] : be2[k * 64 + o];
        int dst = s * 4096 + (((o >> 4) * 128 + (k >> 5) * 64 + ((k >> 3) & 3) * 16 + (o & 15)) << 3) + (k & 7);
        We2b[dst] = (short)bf1(val);
    } else if (bid < 1152) {
        int idx = (bid - 1040) * 256 + tid;
        if (idx < 28672) {
            bool b1 = idx < 16384;
            int li = b1 ? idx : idx - 16384;
            int j = li & 7, lane = (li >> 3) & 63, c = (li >> 9) & 1, otile = li >> 10;
            int k = c * 32 + (lane >> 4) * 8 + j;
            int o = otile * 16 + (lane & 15);
            float val;
            if (b1) val = (o < 64) ? Wroot[k * 64 + o] : gwhh[(o - 64) * 64 + k];
            else    val = gwih[o * 64 + k];
            unsigned hs = bf1(val);
            float lo = val - __uint_as_float(hs << 16);
            unsigned ls = bf1(lo);
            if (b1) { WB1h[li] = (short)hs; WB1l[li] = (short)ls; }
            else    { WB2h[li] = (short)hs; WB2l[li] = (short)ls; }
        }
    } else if (bid < 1280) {
        int idx = (bid - 1152) * 256 + tid;        // < 32768 : lwihT[i*256+j] = lwih[j*128+i]
        int i = idx >> 8, j = idx & 255;
        lwihT[idx] = lwih[j * 128 + i];
    } else if (bid < 1344) {
        int idx = (bid - 1280) * 256 + tid;        // < 16384 : lwhhT[i*256+j] = lwhh[j*64+i]
        int i = idx >> 8, j = idx & 255;
        lwhhT[idx] = lwhh[j * 64 + i];
    } else if (bid < 1349) {
        int i = (bid - 1344) * 256 + tid;
        if (i <= NB) {
            int lo = 0, hi = N_NODES;
            while (lo < hi) { int mid = (lo + hi) >> 1; if (batch[mid] < i) lo = mid + 1; else hi = mid; }
            offs[i] = lo;
        }
    } else if (bid < 6349) {
        int w = tid >> 6, j = tid & 63;
        int n = (bid - 1349) * 4 + w;
        float acc = b0[j];
        const float* xr = x + n * IND;
#pragma unroll
        for (int i = 0; i < IND; ++i) acc = fmaf(xr[i], W0[i * 64 + j], acc);
        hbuf[n * 64 + j] = fmaxf(acc, 0.0f);
    } else if (bid < 18849) {
        int w = tid >> 6, j = tid & 63;
        int e = (bid - 6349) * 4 + w;
        if (e < N_EDGES) {
            float acc = be1[j];
            const float* er = ea + e * 6;
#pragma unroll
            for (int i = 0; i < 6; ++i) acc = fmaf(er[i], We1[i * 64 + j], acc);
            re[e * 64 + j] = fmaxf(acc, 0.0f);
        }
    } else {
        int e = (bid - 18849) * 256 + tid;
        if (e < N_EDGES) atomicAdd(&deg[ei[N_EDGES + e]], 1);
    }
}

__global__ void k_scan(const int* __restrict__ deg, int* __restrict__ rowptr, int* __restrict__ cursor) {
    __shared__ int s_w[16];
    int t = threadIdx.x;
    int base = t * 20;
    int v[20]; int s = 0;
#pragma unroll
    for (int i = 0; i < 20; ++i) {
        int idx = base + i;
        v[i] = (idx < N_NODES) ? deg[idx] : 0;
        s += v[i];
    }
    int lane = t & 63, w = t >> 6;
    int inc = s;
#pragma unroll
    for (int off = 1; off < 64; off <<= 1) {
        int o = __shfl_up(inc, off);
        if (lane >= off) inc += o;
    }
    if (lane == 63) s_w[w] = inc;
    __syncthreads();
    if (w == 0 && lane < 16) {
        int x = s_w[lane];
        int xs = x;
#pragma unroll
        for (int off = 1; off < 16; off <<= 1) {
            int o = __shfl_up(xs, off);
            if (lane >= off) xs += o;
        }
        s_w[lane] = xs - x;
    }
    __syncthreads();
    int run = s_w[w] + (inc - s);
#pragma unroll
    for (int i = 0; i < 20; ++i) {
        int idx = base + i;
        if (idx < N_NODES) { rowptr[idx] = run; cursor[idx] = run; }
        else if (idx == N_NODES) rowptr[idx] = run;
        run += v[i];
    }
}

__global__ void k_fill(const int* __restrict__ ei, int* __restrict__ cursor, int* __restrict__ perm) {
    int e = blockIdx.x * 256 + threadIdx.x;
    if (e < N_EDGES) {
        int pos = atomicAdd(&cursor[ei[N_EDGES + e]], 1);
        perm[pos] = e;
    }
}

// msg kernel — R5/R10 verified structure: 64 edges/block, 256 threads, (256,3), VGPR ~84.
__launch_bounds__(256, 3)
__global__ void k_msg_mfma(const float* __restrict__ hbuf, const float* __restrict__ reb,
                           const short* __restrict__ We2b, const int* __restrict__ ei,
                           float* __restrict__ msg) {
    __shared__ float s_v[64][64];    // [h][e]
    int tid = threadIdx.x;
    int eb = blockIdx.x * 64;
    int lane = tid & 63;
    int w = tid >> 6;
    int l15 = lane & 15, lhi = lane >> 4;

    // stage s_v transposed
    {
        int se = tid >> 2;
        int sh = tid & 3;
        int ge = eb + se;
        const float* rowp = (ge < N_EDGES) ? (hbuf + (size_t)ei[ge] * 64) : (const float*)0;
#pragma unroll
        for (int rr4 = 0; rr4 < 4; ++rr4) {
            int hb = rr4 * 16 + sh * 4;
            float4 vv = rowp ? *(const float4*)(rowp + hb) : make_float4(0.f, 0.f, 0.f, 0.f);
            s_v[hb + 0][se] = vv.x; s_v[hb + 1][se] = vv.y;
            s_v[hb + 2][se] = vv.z; s_v[hb + 3][se] = vv.w;
        }
    }

    // pack re A-fragments once
    union U { int4 i4; bf16x8 v; };
    U a_re[4][2];
#pragma unroll
    for (int m = 0; m < 4; ++m) {
        int ge = eb + m * 16 + l15;
        if (ge < N_EDGES) {
            const float* rp = reb + (size_t)ge * 64 + lhi * 8;
            float4 x0 = *(const float4*)(rp);
            float4 x1 = *(const float4*)(rp + 4);
            float4 y0 = *(const float4*)(rp + 32);
            float4 y1 = *(const float4*)(rp + 36);
            a_re[m][0].i4 = make_int4(pk2(x0.x, x0.y), pk2(x0.z, x0.w), pk2(x1.x, x1.y), pk2(x1.z, x1.w));
            a_re[m][1].i4 = make_int4(pk2(y0.x, y0.y), pk2(y0.z, y0.w), pk2(y1.x, y1.y), pk2(y1.z, y1.w));
        } else {
            a_re[m][0].i4 = make_int4(0, 0, 0, 0);
            a_re[m][1].i4 = make_int4(0, 0, 0, 0);
        }
    }

    // B prefetch: 4 rotating register sets, depth 4
    const int4* bp0 = (const int4*)We2b + (w * 128 + lane);   // slab stride = 512 int4
    const int4* bp1 = bp0 + 64;
    int4 Sc0[4], Sc1[4];
#pragma unroll
    for (int j = 0; j < 4; ++j) {
        Sc0[j] = bp0[j * 512];
        Sc1[j] = bp1[j * 512];
    }

    __syncthreads();

    const f32x4 zero4 = {0.f, 0.f, 0.f, 0.f};
    f32x4 macc[4];
#pragma unroll
    for (int m = 0; m < 4; ++m) macc[m] = zero4;

    // v prefetch depth 1
    float4 vv[4], vn[4];
#pragma unroll
    for (int m = 0; m < 4; ++m) vv[m] = *(const float4*)&s_v[0][m * 16 + lhi * 4];

    for (int g = 0; g < 16; ++g) {
#pragma unroll
        for (int j = 0; j < 4; ++j) {
            int s = g * 4 + j;
            int snext = (s < 63) ? (s + 1) : 63;
#pragma unroll
            for (int m = 0; m < 4; ++m)
                vn[m] = *(const float4*)&s_v[snext][m * 16 + lhi * 4];
            U bb0, bb1; bb0.i4 = Sc0[j]; bb1.i4 = Sc1[j];
#pragma unroll
            for (int m = 0; m < 4; ++m) {
                f32x4 t = __builtin_amdgcn_mfma_f32_16x16x32_bf16(a_re[m][0].v, bb0.v, zero4, 0, 0, 0);
                t = __builtin_amdgcn_mfma_f32_16x16x32_bf16(a_re[m][1].v, bb1.v, t, 0, 0, 0);
                macc[m][0] = fmaf(vv[m].x, t[0], macc[m][0]);
                macc[m][1] = fmaf(vv[m].y, t[1], macc[m][1]);
                macc[m][2] = fmaf(vv[m].z, t[2], macc[m][2]);
                macc[m][3] = fmaf(vv[m].w, t[3], macc[m][3]);
            }
            int sload = (s + 4 <= 64) ? (s + 4) : 64;
            Sc0[j] = bp0[sload * 512];
            Sc1[j] = bp1[sload * 512];
#pragma unroll
            for (int m = 0; m < 4; ++m) vv[m] = vn[m];
        }
    }

    // bias slab (set 0 holds slab 64): msg += v @ be2
    {
        U bb0, bb1; bb0.i4 = Sc0[0]; bb1.i4 = Sc1[0];
#pragma unroll
        for (int m = 0; m < 4; ++m) {
            int e = m * 16 + l15;
            U a0, a1;
            a0.i4 = make_int4(
                pk2(s_v[lhi * 8 + 0][e], s_v[lhi * 8 + 1][e]),
                pk2(s_v[lhi * 8 + 2][e], s_v[lhi * 8 + 3][e]),
                pk2(s_v[lhi * 8 + 4][e], s_v[lhi * 8 + 5][e]),
                pk2(s_v[lhi * 8 + 6][e], s_v[lhi * 8 + 7][e]));
            a1.i4 = make_int4(
                pk2(s_v[32 + lhi * 8 + 0][e], s_v[32 + lhi * 8 + 1][e]),
                pk2(s_v[32 + lhi * 8 + 2][e], s_v[32 + lhi * 8 + 3][e]),
                pk2(s_v[32 + lhi * 8 + 4][e], s_v[32 + lhi * 8 + 5][e]),
                pk2(s_v[32 + lhi * 8 + 6][e], s_v[32 + lhi * 8 + 7][e]));
            macc[m] = __builtin_amdgcn_mfma_f32_16x16x32_bf16(a0.v, bb0.v, macc[m], 0, 0, 0);
            macc[m] = __builtin_amdgcn_mfma_f32_16x16x32_bf16(a1.v, bb1.v, macc[m], 0, 0, 0);
        }
    }
    int o = w * 16 + l15;
#pragma unroll
    for (int m = 0; m < 4; ++m) {
#pragma unroll
        for (int r = 0; r < 4; ++r) {
            int el = m * 16 + lhi * 4 + r;
            int ge = eb + el;
            if (ge < N_EDGES) msg[(size_t)ge * 64 + o] = macc[m][r];
        }
    }
}

// MFMA node update: conv + GRU with split-bf16 weights. 32 nodes / block (625 blocks).
__launch_bounds__(256, 4)
__global__ void k_node_update(float* __restrict__ hbuf, const float* __restrict__ msg,
                              const int* __restrict__ rowptr, const int* __restrict__ perm,
                              const short* __restrict__ WB1h, const short* __restrict__ WB1l,
                              const short* __restrict__ WB2h, const short* __restrict__ WB2l,
                              const float* __restrict__ bconv, const float* __restrict__ bih,
                              const float* __restrict__ bhh) {
    __shared__ short s_hh[32][72];
    __shared__ short s_hl[32][72];
    __shared__ short s_mh[32][72];
    __shared__ short s_ml[32][72];
    __shared__ float s_agg[32][68];
    int tid = threadIdx.x;
    int nbase = blockIdx.x * 32;
    int lane = tid & 63, w = tid >> 6;
    int l15 = lane & 15, lhi = lane >> 4;

    {
        int nt = tid >> 3, q = tid & 7;
        int n = nbase + nt;
#pragma unroll
        for (int c4 = 0; c4 < 2; ++c4) {
            int col = q * 8 + c4 * 4;
            float4 v = *(const float4*)&hbuf[(size_t)n * 64 + col];
            unsigned h01 = pk2(v.x, v.y), h23 = pk2(v.z, v.w);
            float f0 = __uint_as_float(h01 << 16);
            float f1 = __uint_as_float(h01 & 0xffff0000u);
            float f2 = __uint_as_float(h23 << 16);
            float f3 = __uint_as_float(h23 & 0xffff0000u);
            unsigned l01 = pk2(v.x - f0, v.y - f1), l23 = pk2(v.z - f2, v.w - f3);
            *(unsigned*)&s_hh[nt][col]     = h01;
            *(unsigned*)&s_hh[nt][col + 2] = h23;
            *(unsigned*)&s_hl[nt][col]     = l01;
            *(unsigned*)&s_hl[nt][col + 2] = l23;
        }
        float4 aggv[2];
#pragma unroll
        for (int c4 = 0; c4 < 2; ++c4)
            aggv[c4] = *(const float4*)&bconv[q * 8 + c4 * 4];
        int rs = rowptr[n], rend = rowptr[n + 1];
        for (int qq = rs; qq < rend; ++qq) {
            const float* mrow = msg + (size_t)perm[qq] * 64 + q * 8;
#pragma unroll
            for (int c4 = 0; c4 < 2; ++c4) {
                float4 mv = *(const float4*)&mrow[c4 * 4];
                aggv[c4].x += mv.x; aggv[c4].y += mv.y;
                aggv[c4].z += mv.z; aggv[c4].w += mv.w;
            }
        }
#pragma unroll
        for (int c4 = 0; c4 < 2; ++c4)
            *(float4*)&s_agg[nt][q * 8 + c4 * 4] = aggv[c4];
    }
    __syncthreads();

    union U { int4 i4; bf16x8 v; };
    U ah[2][2], al[2][2];
#pragma unroll
    for (int m = 0; m < 2; ++m)
#pragma unroll
        for (int c = 0; c < 2; ++c) {
            ah[m][c].i4 = *(const int4*)&s_hh[m * 16 + l15][c * 32 + lhi * 8];
            al[m][c].i4 = *(const int4*)&s_hl[m * 16 + l15][c * 32 + lhi * 8];
        }

    const int4* B1h = (const int4*)WB1h;
    const int4* B1l = (const int4*)WB1l;
    const int4* B2h = (const int4*)WB2h;
    const int4* B2l = (const int4*)WB2l;

    f32x4 C0[2], G[3][2], I[3][2];

    {
        int ot = w;
        U bh0, bh1, bl0, bl1;
        bh0.i4 = B1h[(ot * 2 + 0) * 64 + lane];
        bh1.i4 = B1h[(ot * 2 + 1) * 64 + lane];
        bl0.i4 = B1l[(ot * 2 + 0) * 64 + lane];
        bl1.i4 = B1l[(ot * 2 + 1) * 64 + lane];
#pragma unroll
        for (int m = 0; m < 2; ++m) {
            f32x4 c;
#pragma unroll
            for (int r = 0; r < 4; ++r) c[r] = s_agg[m * 16 + lhi * 4 + r][w * 16 + l15];
            c = __builtin_amdgcn_mfma_f32_16x16x32_bf16(ah[m][0].v, bh0.v, c, 0, 0, 0);
            c = __builtin_amdgcn_mfma_f32_16x16x32_bf16(ah[m][1].v, bh1.v, c, 0, 0, 0);
            c = __builtin_amdgcn_mfma_f32_16x16x32_bf16(al[m][0].v, bh0.v, c, 0, 0, 0);
            c = __builtin_amdgcn_mfma_f32_16x16x32_bf16(al[m][1].v, bh1.v, c, 0, 0, 0);
            c = __builtin_amdgcn_mfma_f32_16x16x32_bf16(ah[m][0].v, bl0.v, c, 0, 0, 0);
            c = __builtin_amdgcn_mfma_f32_16x16x32_bf16(ah[m][1].v, bl1.v, c, 0, 0, 0);
            C0[m] = c;
        }
    }
#pragma unroll
    for (int m = 0; m < 2; ++m)
#pragma unroll
        for (int r = 0; r < 4; ++r) {
            float mv = fmaxf(C0[m][r], 0.0f);
            int row = m * 16 + lhi * 4 + r, col = w * 16 + l15;
            unsigned hs = bf1(mv);
            float lof = mv - __uint_as_float(hs << 16);
            s_mh[row][col] = (short)hs;
            s_ml[row][col] = (short)bf1(lof);
        }
#pragma unroll
    for (int p = 1; p < 4; ++p) {
        int ot = p * 4 + w;
        U bh0, bh1, bl0, bl1;
        bh0.i4 = B1h[(ot * 2 + 0) * 64 + lane];
        bh1.i4 = B1h[(ot * 2 + 1) * 64 + lane];
        bl0.i4 = B1l[(ot * 2 + 0) * 64 + lane];
        bl1.i4 = B1l[(ot * 2 + 1) * 64 + lane];
        float bv = bhh[(p - 1) * 64 + w * 16 + l15];
#pragma unroll
        for (int m = 0; m < 2; ++m) {
            f32x4 c = {bv, bv, bv, bv};
            c = __builtin_amdgcn_mfma_f32_16x16x32_bf16(ah[m][0].v, bh0.v, c, 0, 0, 0);
            c = __builtin_amdgcn_mfma_f32_16x16x32_bf16(ah[m][1].v, bh1.v, c, 0, 0, 0);
            c = __builtin_amdgcn_mfma_f32_16x16x32_bf16(al[m][0].v, bh0.v, c, 0, 0, 0);
            c = __builtin_amdgcn_mfma_f32_16x16x32_bf16(al[m][1].v, bh1.v, c, 0, 0, 0);
            c = __builtin_amdgcn_mfma_f32_16x16x32_bf16(ah[m][0].v, bl0.v, c, 0, 0, 0);
            c = __builtin_amdgcn_mfma_f32_16x16x32_bf16(ah[m][1].v, bl1.v, c, 0, 0, 0);
            G[p - 1][m] = c;
        }
    }
    __syncthreads();
    U mh[2][2], ml[2][2];
#pragma unroll
    for (int m = 0; m < 2; ++m)
#pragma unroll
        for (int c = 0; c < 2; ++c) {
            mh[m][c].i4 = *(const int4*)&s_mh[m * 16 + l15][c * 32 + lhi * 8];
            ml[m][c].i4 = *(const int4*)&s_ml[m * 16 + l15][c * 32 + lhi * 8];
        }
#pragma unroll
    for (int p = 0; p < 3; ++p) {
        int ot = p * 4 + w;
        U bh0, bh1, bl0, bl1;
        bh0.i4 = B2h[(ot * 2 + 0) * 64 + lane];
        bh1.i4 = B2h[(ot * 2 + 1) * 64 + lane];
        bl0.i4 = B2l[(ot * 2 + 0) * 64 + lane];
        bl1.i4 = B2l[(ot * 2 + 1) * 64 + lane];
        float bv = bih[p * 64 + w * 16 + l15];
#pragma unroll
        for (int m = 0; m < 2; ++m) {
            f32x4 c = {bv, bv, bv, bv};
            c = __builtin_amdgcn_mfma_f32_16x16x32_bf16(mh[m][0].v, bh0.v, c, 0, 0, 0);
            c = __builtin_amdgcn_mfma_f32_16x16x32_bf16(mh[m][1].v, bh1.v, c, 0, 0, 0);
            c = __builtin_amdgcn_mfma_f32_16x16x32_bf16(ml[m][0].v, bh0.v, c, 0, 0, 0);
            c = __builtin_amdgcn_mfma_f32_16x16x32_bf16(ml[m][1].v, bh1.v, c, 0, 0, 0);
            c = __builtin_amdgcn_mfma_f32_16x16x32_bf16(mh[m][0].v, bl0.v, c, 0, 0, 0);
            c = __builtin_amdgcn_mfma_f32_16x16x32_bf16(mh[m][1].v, bl1.v, c, 0, 0, 0);
            I[p][m] = c;
        }
    }
#pragma unroll
    for (int m = 0; m < 2; ++m)
#pragma unroll
        for (int r = 0; r < 4; ++r) {
            int row = m * 16 + lhi * 4 + r;
            int n = nbase + row;
            int col = w * 16 + l15;
            float hold = __uint_as_float(((unsigned)(unsigned short)s_hh[row][col]) << 16)
                       + __uint_as_float(((unsigned)(unsigned short)s_hl[row][col]) << 16);
            float rg = sigmoidf_(I[0][m][r] + G[0][m][r]);
            float z  = sigmoidf_(I[1][m][r] + G[1][m][r]);
            float nn = tanhf_(I[2][m][r] + rg * G[2][m][r]);
            hbuf[(size_t)n * 64 + col] = (1.0f - z) * nn + z * hold;
        }
}

// Fused Set2Set (3 iterations) + readout MLP. 256 threads (4 waves) per graph.
__launch_bounds__(256)
__global__ void k_set2set(const float* __restrict__ hbuf, const int* __restrict__ offs,
                          const float* __restrict__ t, const float* __restrict__ p,
                          const float* __restrict__ lwihT, const float* __restrict__ lwhhT,
                          const float* __restrict__ l_bih, const float* __restrict__ l_bhh,
                          const float* __restrict__ W1, const float* __restrict__ b1,
                          const float* __restrict__ W2, const float* __restrict__ b2,
                          const float* __restrict__ W3, const float* __restrict__ b3,
                          float* __restrict__ y) {
    __shared__ float s_qs[192];       // [0..127]=q_star, [128..191]=qh
    __shared__ float s_g[256];
    __shared__ float s_racc[4][64];
    __shared__ float s_m[4], s_l[4];
    __shared__ float s_y[64];
    int b = blockIdx.x;
    int tid = threadIdx.x;
    int w = tid >> 6, lane = tid & 63;
    int s = offs[b], e = offs[b + 1];
    float bi = l_bih[tid] + l_bhh[tid];
    float qc = 0.f;                   // live in wave-0 lanes

    if (tid < 192) s_qs[tid] = 0.f;
    __syncthreads();

    for (int iter = 0; iter < 3; ++iter) {
        float g = bi;
#pragma unroll 8
        for (int i = 0; i < 128; ++i) g = fmaf(s_qs[i], lwihT[i * 256 + tid], g);
#pragma unroll 8
        for (int i = 0; i < 64; ++i)  g = fmaf(s_qs[128 + i], lwhhT[i * 256 + tid], g);
        s_g[tid] = g;
        __syncthreads();
        if (w == 0) {
            float ci = sigmoidf_(s_g[lane]);
            float cf = sigmoidf_(s_g[64 + lane]);
            float cg = tanhf_(s_g[128 + lane]);
            float co = sigmoidf_(s_g[192 + lane]);
            qc = cf * qc + ci * cg;
            float qh = co * tanhf_(qc);
            s_qs[lane] = qh;
            s_qs[128 + lane] = qh;
        }
        __syncthreads();
        float qv = s_qs[128 + lane];
        float mx = -1e30f, l = 0.0f, racc = 0.0f;
        for (int n = s + w; n < e; n += 4) {
            float xv = hbuf[(size_t)n * 64 + lane];
            float prod = xv * qv;
#pragma unroll
            for (int off = 32; off > 0; off >>= 1) prod += __shfl_xor(prod, off);
            float mnew = fmaxf(mx, prod);
            float scale = __expf(mx - mnew);
            float wgt = __expf(prod - mnew);
            l = l * scale + wgt;
            racc = racc * scale + wgt * xv;
            mx = mnew;
        }
        s_racc[w][lane] = racc;
        if (lane == 0) { s_m[w] = mx; s_l[w] = l; }
        __syncthreads();
        if (w == 0) {
            float M = fmaxf(fmaxf(s_m[0], s_m[1]), fmaxf(s_m[2], s_m[3]));
            float L = 0.f, R = 0.f;
#pragma unroll
            for (int ww = 0; ww < 4; ++ww) {
                float sc = __expf(s_m[ww] - M);
                L += s_l[ww] * sc;
                R = fmaf(s_racc[ww][lane], sc, R);
            }
            s_qs[64 + lane] = (e > s) ? (R / L) : 0.0f;
        }
        __syncthreads();
    }
    if (w == 0) {
        float acc = b1[lane];
#pragma unroll 8
        for (int i = 0; i < 128; ++i) acc = fmaf(s_qs[i], W1[i * 64 + lane], acc);
        acc = fmaf(t[b], W1[128 * 64 + lane], acc);
        acc = fmaf(p[b], W1[129 * 64 + lane], acc);
        acc = fmaxf(acc, 0.0f);
        s_y[lane] = acc;
        float acc2 = b2[lane];
#pragma unroll 8
        for (int i = 0; i < 64; ++i) acc2 = fmaf(s_y[i], W2[i * 64 + lane], acc2);
        acc2 = fmaxf(acc2, 0.0f);
        float part = acc2 * W3[lane];
#pragma unroll
        for (int off = 32; off > 0; off >>= 1) part += __shfl_xor(part, off);
        if (lane == 0) y[b] = part + b3[0];
    }
}

extern "C" void kernel_launch(void* const* d_in, const int* in_sizes, int n_in,
                              void* d_out, int out_size, void* d_ws, size_t ws_size,
                              hipStream_t stream) {
    const float* x     = (const float*)d_in[0];
    const int*   ei    = (const int*)  d_in[1];
    const float* ea    = (const float*)d_in[2];
    const int*   batch = (const int*)  d_in[3];
    const float* t     = (const float*)d_in[4];
    const float* p     = (const float*)d_in[5];
    const float* W0    = (const float*)d_in[7];
    const float* b0    = (const float*)d_in[8];
    const float* We1   = (const float*)d_in[9];
    const float* be1   = (const float*)d_in[10];
    const float* We2   = (const float*)d_in[11];
    const float* be2   = (const float*)d_in[12];
    const float* Wroot = (const float*)d_in[13];
    const float* bconv = (const float*)d_in[14];
    const float* gwih  = (const float*)d_in[15];
    const float* gwhh  = (const float*)d_in[16];
    const float* gbih  = (const float*)d_in[17];
    const float* gbhh  = (const float*)d_in[18];
    const float* lwih  = (const float*)d_in[19];
    const float* lwhh  = (const float*)d_in[20];
    const float* lbih  = (const float*)d_in[21];
    const float* lbhh  = (const float*)d_in[22];
    const float* W1    = (const float*)d_in[23];
    const float* b1    = (const float*)d_in[24];
    const float* W2    = (const float*)d_in[25];
    const float* b2    = (const float*)d_in[26];
    const float* W3    = (const float*)d_in[27];
    const float* b3    = (const float*)d_in[28];
    float* y = (float*)d_out;

    char* ws = (char*)d_ws;
    size_t off = 0;
    auto alloc = [&](size_t nbytes) {
        void* ptr = (void*)(ws + off);
        off += align_up(nbytes, 256);
        return ptr;
    };
    float* hbuf   = (float*)alloc((size_t)N_NODES * 64 * 4);
    float* reb    = (float*)alloc((size_t)N_EDGES * 64 * 4);
    float* msg    = (float*)alloc((size_t)N_EDGES * 64 * 4);
    short* We2b   = (short*)alloc((size_t)65 * 4096 * 2);
    short* WB1h   = (short*)alloc(16384 * 2);
    short* WB1l   = (short*)alloc(16384 * 2);
    short* WB2h   = (short*)alloc(12288 * 2);
    short* WB2l   = (short*)alloc(12288 * 2);
    float* lwihT  = (float*)alloc(32768 * 4);
    float* lwhhT  = (float*)alloc(16384 * 4);
    int*   offs   = (int*)  alloc((NB + 1) * 4);
    int*   deg    = (int*)  alloc(N_NODES * 4);
    int*   rowptr = (int*)  alloc((N_NODES + 1) * 4);
    int*   cursor = (int*)  alloc(N_NODES * 4);
    int*   perm   = (int*)  alloc(N_EDGES * 4);

    // ---- deg zero FIRST (stream-ordered before k_prep's count blocks) ----
    hipMemsetAsync(deg, 0, (size_t)N_NODES * 4, stream);
    // ---- mega-prep (prep + encoder + edge count) + CSR scan/fill ----
    k_prep<<<19045, 256, 0, stream>>>(We2, be2, We2b, Wroot, gwhh, gwih,
                                      WB1h, WB1l, WB2h, WB2l,
                                      lwih, lwhh, lwihT, lwhhT, batch, offs,
                                      x, W0, b0, hbuf, ea, We1, be1, reb,
                                      ei, deg);
    k_scan<<<1, 1024, 0, stream>>>(deg, rowptr, cursor);
    k_fill<<<(N_EDGES + 255) / 256, 256, 0, stream>>>(ei, cursor, perm);

    // ---- 4 message-passing + GRU iterations ----
    for (int it = 0; it < 4; ++it) {
        k_msg_mfma<<<(N_EDGES + 63) / 64, 256, 0, stream>>>(hbuf, reb, We2b, ei, msg);
        k_node_update<<<N_NODES / 32, 256, 0, stream>>>(hbuf, msg, rowptr, perm,
                                                        WB1h, WB1l, WB2h, WB2l,
                                                        bconv, gbih, gbhh);
    }

    // ---- fused Set2Set (3 iters) + readout ----
    k_set2set<<<NB, 256, 0, stream>>>(hbuf, offs, t, p, lwihT, lwhhT, lbih, lbhh,
                                      W1, b1, W2, b2, W3, b3, y);
}